// Round 1
// 281.895 us; speedup vs baseline: 1.1227x; 1.1227x over previous
//
#include <hip/hip_runtime.h>
#include <hip/hip_bf16.h>

#define N_EMBD 1024
#define N_HEADS 16
#define HD 64
#define TSEQ 2048
#define BATCH 4
#define M_TOT (BATCH*TSEQ)   // 8192

typedef short s16x8 __attribute__((ext_vector_type(8)));
typedef float f32x4 __attribute__((ext_vector_type(4)));

__device__ __forceinline__ void glds16(const void* g, void* l) {
  __builtin_amdgcn_global_load_lds((const __attribute__((address_space(1))) void*)g,
                                   (__attribute__((address_space(3))) void*)l, 16, 0, 0);
}

// ---- cast x fp32 -> bf16, 4 elems/thread ----
__global__ __launch_bounds__(256) void xcast_kernel(const float* __restrict__ x,
                                                    __hip_bfloat16* __restrict__ xb) {
  int i = blockIdx.x * 256 + threadIdx.x;
  float4 f = ((const float4*)x)[i];
  __hip_bfloat162 p0, p1;
  p0.x = __float2bfloat16(f.x); p0.y = __float2bfloat16(f.y);
  p1.x = __float2bfloat16(f.z); p1.y = __float2bfloat16(f.w);
  ((__hip_bfloat162*)xb)[2*i]   = p0;
  ((__hip_bfloat162*)xb)[2*i+1] = p1;
}

// ---- transpose + cast weights: out[n][c] = in[c][n], bf16 ----
__global__ void wcast_kernel(const float* __restrict__ Wq, const float* __restrict__ Wk,
                             const float* __restrict__ Wv, const float* __restrict__ Wp,
                             __hip_bfloat16* __restrict__ wqkvt, __hip_bfloat16* __restrict__ wpt) {
  __shared__ float tile[32][33];
  int z = blockIdx.z;
  const float* in = (z==0)?Wq:(z==1)?Wk:(z==2)?Wv:Wp;
  __hip_bfloat16* out = (z<3) ? (wqkvt + (size_t)z*N_EMBD*N_EMBD) : wpt;
  int tx = threadIdx.x, ty = threadIdx.y;
  int x  = blockIdx.x*32 + tx;
  int y0 = blockIdx.y*32;
  #pragma unroll
  for (int j=0;j<4;++j) tile[ty + j*8][tx] = in[(size_t)(y0+ty+j*8)*N_EMBD + x];
  __syncthreads();
  int xo  = y0 + tx;
  int yo0 = blockIdx.x*32;
  #pragma unroll
  for (int j=0;j<4;++j)
    out[(size_t)(yo0+ty+j*8)*N_EMBD + xo] = __float2bfloat16(tile[tx][ty+j*8]);
}

// ---- bf16 MFMA GEMM, m97-style: 128x128 tile, BK=64, glds16 staging ----
// LDS layout is XOR-swizzled on the GLOBAL fetch side: physical 16B-group g
// holds logical group g^(row&7)  (glds LDS side must stay linear lane*16).
// mode 0: N=3072 (QKV). Q,K scatter [B,H,T,d]; V stored TRANSPOSED [B,H,d,T].
// mode 1: N=1024 (proj), out fp32 = acc + bias.
__global__ __launch_bounds__(256) void gemm_kernel(
    const __hip_bfloat16* __restrict__ A,   // [M][1024] bf16
    const __hip_bfloat16* __restrict__ Bt,  // [N][1024] bf16 (transposed weight)
    __hip_bfloat16* __restrict__ Qb, __hip_bfloat16* __restrict__ Kb,
    __hip_bfloat16* __restrict__ Vt,        // [B,H,d,T]
    float* __restrict__ out, const float* __restrict__ bias, int mode) {
  __shared__ __align__(16) char smem[32768];
  __hip_bfloat16* Alin = (__hip_bfloat16*)smem;            // 128x64
  __hip_bfloat16* Blin = (__hip_bfloat16*)(smem + 16384);  // 128x64
  int tid = threadIdx.x;
  int m0 = blockIdx.y*128, n0 = blockIdx.x*128;
  int w = tid>>6, lane = tid&63, l16 = lane&15, quad = lane>>4;
  int wr = w>>1, wc = w&1;
  int xg = l16 & 7;
  int off0 = ((quad    ) ^ xg)*8;   // physical col offset for logical k-chunk 0
  int off1 = ((quad + 4) ^ xg)*8;   // logical group c*4+quad, c=1
  f32x4 acc[4][4];
  #pragma unroll
  for (int mi=0;mi<4;++mi)
    #pragma unroll
    for (int ni=0;ni<4;++ni) acc[mi][ni] = (f32x4){0.f,0.f,0.f,0.f};

  for (int k0=0; k0<N_EMBD; k0+=64) {
    __syncthreads();   // prev frag reads done before restaging
    #pragma unroll
    for (int rd=0; rd<4; ++rd) {
      int slot = rd*256 + tid;
      int row  = slot>>3;
      int gc8  = ((tid&7) ^ (row&7))*8;
      glds16(A  + (size_t)(m0+row)*N_EMBD + k0 + gc8, Alin + slot*8);
      glds16(Bt + (size_t)(n0+row)*N_EMBD + k0 + gc8, Blin + slot*8);
    }
    __syncthreads();   // drain vmcnt
    #pragma unroll
    for (int c=0;c<2;++c) {
      int off = c ? off1 : off0;
      s16x8 af[4], bfr[4];
      #pragma unroll
      for (int mi=0;mi<4;++mi)
        af[mi] = *(const s16x8*)(Alin + (wr*64+mi*16+l16)*64 + off);
      #pragma unroll
      for (int ni=0;ni<4;++ni)
        bfr[ni] = *(const s16x8*)(Blin + (wc*64+ni*16+l16)*64 + off);
      #pragma unroll
      for (int mi=0;mi<4;++mi)
        #pragma unroll
        for (int ni=0;ni<4;++ni)
          acc[mi][ni] = __builtin_amdgcn_mfma_f32_16x16x32_bf16(af[mi], bfr[ni], acc[mi][ni],0,0,0);
    }
  }

  if (mode == 0) {
    int which = n0 >> 10;
    int bb = m0 >> 11, t0 = m0 & 2047;
    if (which < 2) {
      __hip_bfloat16* outp = (which==0)?Qb:Kb;
      #pragma unroll
      for (int mi=0;mi<4;++mi) {
        #pragma unroll
        for (int ni=0;ni<4;++ni) {
          int ncol = (n0 & 1023) + wc*64 + ni*16 + l16;
          int hh = ncol>>6, dd = ncol&63;
          #pragma unroll
          for (int r=0;r<4;++r) {
            int t = t0 + wr*64 + mi*16 + quad*4 + r;
            outp[((size_t)(bb*N_HEADS + hh)*TSEQ + t)*HD + dd] = __float2bfloat16(acc[mi][ni][r]);
          }
        }
      }
    } else {
      // V: transpose 128x128 tile (2 heads) in LDS, store [B,H,d,T]
      int hh0 = (n0 & 1023) >> 6;
      __hip_bfloat16 (*Ts)[136] = (__hip_bfloat16(*)[136])smem;  // 64x136x2=17408
      #pragma unroll
      for (int p=0;p<2;++p) {
        __syncthreads();   // Ts region free (prev frag reads / prev pass stores done)
        if (wc == p) {
          #pragma unroll
          for (int mi=0;mi<4;++mi)
            #pragma unroll
            for (int ni=0;ni<4;++ni) {
              int dd = ni*16 + l16;
              #pragma unroll
              for (int r=0;r<4;++r)
                Ts[dd][wr*64 + mi*16 + quad*4 + r] = __float2bfloat16(acc[mi][ni][r]);
            }
        }
        __syncthreads();
        int dd = tid>>2, tc = (tid&3)*32;
        __hip_bfloat16* dst = Vt + ((size_t)(bb*N_HEADS + hh0 + p)*HD + dd)*TSEQ + t0 + tc;
        #pragma unroll
        for (int c4=0;c4<4;++c4)
          *(uint4*)(dst + c4*8) = *(const uint4*)&Ts[dd][tc + c4*8];
      }
    }
  } else {
    #pragma unroll
    for (int mi=0;mi<4;++mi) {
      #pragma unroll
      for (int ni=0;ni<4;++ni) {
        int col = n0 + wc*64 + ni*16 + l16;
        float bs = bias[col];
        #pragma unroll
        for (int r=0;r<4;++r) {
          int m = m0 + wr*64 + mi*16 + quad*4 + r;
          out[(size_t)m*N_EMBD + col] = acc[mi][ni][r] + bs;
        }
      }
    }
  }
}

// ---- MFMA causal flash attention, 128 queries/block, 32 q/wave ----
// K/V staged via glds16 (XOR-swizzled global fetch). P round-trips through
// Ps with row stride 68 bf16 (136B): rows hold 64 data + 4 pad. P-writes hit
// banks (quad*8 + l16/2)%32 -> 2-way only (free); frag reads are 2x 8B loads
// (every offset is a multiple of 8B).
//
// R0 (this round): causal LOAD BALANCE. Grid (16,16,4) = exactly 4 blocks/CU
// resident (LDS 33KB caps at 4); dispatch gives a CU blocks {l, l+256, l+512,
// l+768} = same (bx,by), bz=0..3. With qb=bx, a CU's 4 blocks all share qb ->
// per-CU work spans 8..128 k-tiles (avg 68): makespan 1.88x ideal, matching
// Occupancy=13.7% / MfmaUtil=10.4%. Fix: reflect qb on odd bz so each CU gets
// (2bx+2)+(32-2bx)+(2bx+2)+(32-2bx) = 68 tiles exactly. Bijective per bz.
// Also: wave-uniform skip of the causal compare on fully-unmasked tiles
// (all but the last 2 tiles of each band).
#define PST 68
__global__ __launch_bounds__(256) void attn_kernel(
    const __hip_bfloat16* __restrict__ Qb, const __hip_bfloat16* __restrict__ Kb,
    const __hip_bfloat16* __restrict__ Vt, __hip_bfloat16* __restrict__ Yb) {
  __shared__ __align__(16) __hip_bfloat16 Ks[64][64];    // [key][d] swizzled
  __shared__ __align__(16) __hip_bfloat16 Vs[64][64];    // [d][key] swizzled
  __shared__ __align__(16) __hip_bfloat16 Ps[128][PST];  // [q][key]
  int tid = threadIdx.x;
  int b = blockIdx.z, h = blockIdx.y;
  int qb = (b & 1) ? (TSEQ/128 - 1 - blockIdx.x) : blockIdx.x;  // R0 balance remap
  int q0 = qb*128;
  size_t bhT  = (size_t)(b*N_HEADS + h)*TSEQ;
  size_t bhHD = (size_t)(b*N_HEADS + h)*HD;
  int lane = tid&63, w = tid>>6, l16 = lane&15, quad = lane>>4;
  int wq = w*32;                       // wave's query band
  int xg = l16 & 7;
  int off0 = ((quad    ) ^ xg)*8;
  int off1 = ((quad + 4) ^ xg)*8;

  // Q fragments (A-layout) for 2 q-tiles x 2 k-chunks
  s16x8 qf[2][2];
  #pragma unroll
  for (int mi=0;mi<2;++mi) {
    const __hip_bfloat16* qrow = Qb + (bhT + q0 + wq + mi*16 + l16)*HD;
    qf[mi][0] = *(const s16x8*)(qrow + quad*8);
    qf[mi][1] = *(const s16x8*)(qrow + 32 + quad*8);
  }

  f32x4 z4 = {0.f,0.f,0.f,0.f};
  f32x4 oacc[4][2];
  #pragma unroll
  for (int ni=0;ni<4;++ni) { oacc[ni][0]=z4; oacc[ni][1]=z4; }
  float lrow[2][4] = {{0.f,0.f,0.f,0.f},{0.f,0.f,0.f,0.f}};

  int ntiles = 2*qb + 2;
  for (int t=0; t<ntiles; ++t) {
    int k0 = t*64;
    __syncthreads();   // prev tile frag reads done before restaging
    #pragma unroll
    for (int rd=0; rd<2; ++rd) {
      int slot = rd*256 + tid;
      int row  = slot>>3;
      int gc8  = ((tid&7) ^ (row&7))*8;
      glds16(Kb + (bhT + k0 + row)*HD + gc8,       &Ks[0][0] + slot*8);
      glds16(Vt + (bhHD + row)*TSEQ + k0 + gc8,    &Vs[0][0] + slot*8);
    }
    __syncthreads();   // drain vmcnt

    // S = Q K^T : 32q x 64key per wave
    f32x4 sacc[4][2];
    #pragma unroll
    for (int ni=0; ni<4; ++ni) {
      s16x8 kb0 = *(const s16x8*)(&Ks[0][0] + (ni*16+l16)*64 + off0);
      s16x8 kb1 = *(const s16x8*)(&Ks[0][0] + (ni*16+l16)*64 + off1);
      #pragma unroll
      for (int mi=0; mi<2; ++mi) {
        f32x4 s = z4;
        s = __builtin_amdgcn_mfma_f32_16x16x32_bf16(qf[mi][0], kb0, s,0,0,0);
        s = __builtin_amdgcn_mfma_f32_16x16x32_bf16(qf[mi][1], kb1, s,0,0,0);
        sacc[ni][mi] = s;
      }
    }

    // mask + exp; accumulate l; P -> LDS (own band; same-wave lgkmcnt ordering)
    // wave-uniform: min query row of this wave = q0+wq; max key col = k0+63.
    if (q0 + wq >= k0 + 63) {
      // fully unmasked tile for this wave: no compare needed
      #pragma unroll
      for (int ni=0; ni<4; ++ni) {
        #pragma unroll
        for (int mi=0; mi<2; ++mi) {
          #pragma unroll
          for (int r=0; r<4; ++r) {
            float p = __expf(sacc[ni][mi][r]*0.125f);
            lrow[mi][r] += p;
            Ps[wq + mi*16 + quad*4 + r][ni*16 + l16] = __float2bfloat16(p);
          }
        }
      }
    } else {
      #pragma unroll
      for (int ni=0; ni<4; ++ni) {
        int kcol = k0 + ni*16 + l16;
        #pragma unroll
        for (int mi=0; mi<2; ++mi) {
          int qrb = q0 + wq + mi*16 + quad*4;
          #pragma unroll
          for (int r=0; r<4; ++r) {
            float p = (qrb + r >= kcol) ? __expf(sacc[ni][mi][r]*0.125f) : 0.f;
            lrow[mi][r] += p;
            Ps[wq + mi*16 + quad*4 + r][ni*16 + l16] = __float2bfloat16(p);
          }
        }
      }
    }

    // O += P V
    union U8 { s16x8 v; uint2 u[2]; };
    U8 aP[2][2];
    #pragma unroll
    for (int mi=0; mi<2; ++mi)
      #pragma unroll
      for (int c=0; c<2; ++c) {
        const __hip_bfloat16* pr = &Ps[wq + mi*16 + l16][c*32 + quad*8];
        aP[mi][c].u[0] = *(const uint2*)pr;
        aP[mi][c].u[1] = *(const uint2*)(pr + 4);
      }
    #pragma unroll
    for (int ni=0; ni<4; ++ni) {
      s16x8 vb0 = *(const s16x8*)(&Vs[0][0] + (ni*16+l16)*64 + off0);
      s16x8 vb1 = *(const s16x8*)(&Vs[0][0] + (ni*16+l16)*64 + off1);
      #pragma unroll
      for (int mi=0; mi<2; ++mi) {
        oacc[ni][mi] = __builtin_amdgcn_mfma_f32_16x16x32_bf16(aP[mi][0].v, vb0, oacc[ni][mi],0,0,0);
        oacc[ni][mi] = __builtin_amdgcn_mfma_f32_16x16x32_bf16(aP[mi][1].v, vb1, oacc[ni][mi],0,0,0);
      }
    }
  }

  // reduce l across the 16 lanes of each quad-row group
  #pragma unroll
  for (int off=1; off<16; off<<=1)
    #pragma unroll
    for (int mi=0; mi<2; ++mi)
      #pragma unroll
      for (int r=0; r<4; ++r) lrow[mi][r] += __shfl_xor(lrow[mi][r], off);

  #pragma unroll
  for (int mi=0; mi<2; ++mi)
    #pragma unroll
    for (int r=0; r<4; ++r) {
      float inv = 1.f / lrow[mi][r];
      int tq = q0 + wq + mi*16 + quad*4 + r;
      __hip_bfloat16* yr = Yb + ((size_t)(b*TSEQ + tq))*N_EMBD + h*HD;
      #pragma unroll
      for (int ni=0; ni<4; ++ni)
        yr[ni*16 + l16] = __float2bfloat16(oacc[ni][mi][r] * inv);
    }
}

extern "C" void kernel_launch(void* const* d_in, const int* in_sizes, int n_in,
                              void* d_out, int out_size, void* d_ws, size_t ws_size,
                              hipStream_t stream) {
  const float* x  = (const float*)d_in[0];
  const float* Wq = (const float*)d_in[1];
  const float* Wk = (const float*)d_in[2];
  const float* Wv = (const float*)d_in[3];
  const float* Wp = (const float*)d_in[4];
  const float* bp = (const float*)d_in[5];

  char* w = (char*)d_ws;
  __hip_bfloat16* xb    = (__hip_bfloat16*)w;  w += (size_t)M_TOT*N_EMBD*2;   // 16 MB
  __hip_bfloat16* wqkvt = (__hip_bfloat16*)w;  w += (size_t)3*N_EMBD*N_EMBD*2;// 6 MB
  __hip_bfloat16* wpt   = (__hip_bfloat16*)w;  w += (size_t)N_EMBD*N_EMBD*2;  // 2 MB
  __hip_bfloat16* Qb    = (__hip_bfloat16*)w;  w += (size_t)M_TOT*N_EMBD*2;   // 16 MB
  __hip_bfloat16* Kb    = (__hip_bfloat16*)w;  w += (size_t)M_TOT*N_EMBD*2;   // 16 MB
  __hip_bfloat16* Vt    = (__hip_bfloat16*)w;  w += (size_t)M_TOT*N_EMBD*2;   // 16 MB [B,H,d,T]
  __hip_bfloat16* Yb    = (__hip_bfloat16*)w;                                  // 16 MB (88 MB total)

  xcast_kernel<<<dim3(M_TOT*N_EMBD/1024), dim3(256), 0, stream>>>(x, xb);
  wcast_kernel<<<dim3(32,32,4), dim3(32,8), 0, stream>>>(Wq,Wk,Wv,Wp,wqkvt,wpt);
  gemm_kernel<<<dim3(24,64), dim3(256), 0, stream>>>(xb, wqkvt, Qb,Kb,Vt, nullptr, nullptr, 0);
  attn_kernel<<<dim3(TSEQ/128,N_HEADS,BATCH), dim3(256), 0, stream>>>(Qb,Kb,Vt,Yb);
  gemm_kernel<<<dim3(8,64), dim3(256), 0, stream>>>(Yb, wpt, nullptr,nullptr,nullptr,
                                                    (float*)d_out, bp, 1);
}

// Round 2
// 278.373 us; speedup vs baseline: 1.1369x; 1.0127x over previous
//
#include <hip/hip_runtime.h>
#include <hip/hip_bf16.h>

#define N_EMBD 1024
#define N_HEADS 16
#define HD 64
#define TSEQ 2048
#define BATCH 4
#define M_TOT (BATCH*TSEQ)   // 8192

typedef short s16x8 __attribute__((ext_vector_type(8)));
typedef float f32x4 __attribute__((ext_vector_type(4)));

__device__ __forceinline__ void glds16(const void* g, void* l) {
  __builtin_amdgcn_global_load_lds((const __attribute__((address_space(1))) void*)g,
                                   (__attribute__((address_space(3))) void*)l, 16, 0, 0);
}

// ---- cast x fp32 -> bf16, 4 elems/thread ----
__global__ __launch_bounds__(256) void xcast_kernel(const float* __restrict__ x,
                                                    __hip_bfloat16* __restrict__ xb) {
  int i = blockIdx.x * 256 + threadIdx.x;
  float4 f = ((const float4*)x)[i];
  __hip_bfloat162 p0, p1;
  p0.x = __float2bfloat16(f.x); p0.y = __float2bfloat16(f.y);
  p1.x = __float2bfloat16(f.z); p1.y = __float2bfloat16(f.w);
  ((__hip_bfloat162*)xb)[2*i]   = p0;
  ((__hip_bfloat162*)xb)[2*i+1] = p1;
}

// ---- transpose + cast weights: out[n][c] = in[c][n], bf16 ----
__global__ void wcast_kernel(const float* __restrict__ Wq, const float* __restrict__ Wk,
                             const float* __restrict__ Wv, const float* __restrict__ Wp,
                             __hip_bfloat16* __restrict__ wqkvt, __hip_bfloat16* __restrict__ wpt) {
  __shared__ float tile[32][33];
  int z = blockIdx.z;
  const float* in = (z==0)?Wq:(z==1)?Wk:(z==2)?Wv:Wp;
  __hip_bfloat16* out = (z<3) ? (wqkvt + (size_t)z*N_EMBD*N_EMBD) : wpt;
  int tx = threadIdx.x, ty = threadIdx.y;
  int x  = blockIdx.x*32 + tx;
  int y0 = blockIdx.y*32;
  #pragma unroll
  for (int j=0;j<4;++j) tile[ty + j*8][tx] = in[(size_t)(y0+ty+j*8)*N_EMBD + x];
  __syncthreads();
  int xo  = y0 + tx;
  int yo0 = blockIdx.x*32;
  #pragma unroll
  for (int j=0;j<4;++j)
    out[(size_t)(yo0+ty+j*8)*N_EMBD + xo] = __float2bfloat16(tile[tx][ty+j*8]);
}

// ---- bf16 MFMA GEMM, m97-style: 128x128 tile, BK=64, glds16 staging ----
// LDS layout is XOR-swizzled on the GLOBAL fetch side: physical 16B-group g
// holds logical group g^(row&7)  (glds LDS side must stay linear lane*16).
// mode 0: N=3072 (QKV). Q,K scatter [B,H,T,d]; V stored TRANSPOSED [B,H,d,T].
// mode 1: N=1024 (proj), out fp32 = acc + bias.
__global__ __launch_bounds__(256) void gemm_kernel(
    const __hip_bfloat16* __restrict__ A,   // [M][1024] bf16
    const __hip_bfloat16* __restrict__ Bt,  // [N][1024] bf16 (transposed weight)
    __hip_bfloat16* __restrict__ Qb, __hip_bfloat16* __restrict__ Kb,
    __hip_bfloat16* __restrict__ Vt,        // [B,H,d,T]
    float* __restrict__ out, const float* __restrict__ bias, int mode) {
  __shared__ __align__(16) char smem[32768];
  __hip_bfloat16* Alin = (__hip_bfloat16*)smem;            // 128x64
  __hip_bfloat16* Blin = (__hip_bfloat16*)(smem + 16384);  // 128x64
  int tid = threadIdx.x;
  int m0 = blockIdx.y*128, n0 = blockIdx.x*128;
  int w = tid>>6, lane = tid&63, l16 = lane&15, quad = lane>>4;
  int wr = w>>1, wc = w&1;
  int xg = l16 & 7;
  int off0 = ((quad    ) ^ xg)*8;   // physical col offset for logical k-chunk 0
  int off1 = ((quad + 4) ^ xg)*8;   // logical group c*4+quad, c=1
  f32x4 acc[4][4];
  #pragma unroll
  for (int mi=0;mi<4;++mi)
    #pragma unroll
    for (int ni=0;ni<4;++ni) acc[mi][ni] = (f32x4){0.f,0.f,0.f,0.f};

  for (int k0=0; k0<N_EMBD; k0+=64) {
    __syncthreads();   // prev frag reads done before restaging
    #pragma unroll
    for (int rd=0; rd<4; ++rd) {
      int slot = rd*256 + tid;
      int row  = slot>>3;
      int gc8  = ((tid&7) ^ (row&7))*8;
      glds16(A  + (size_t)(m0+row)*N_EMBD + k0 + gc8, Alin + slot*8);
      glds16(Bt + (size_t)(n0+row)*N_EMBD + k0 + gc8, Blin + slot*8);
    }
    __syncthreads();   // drain vmcnt
    #pragma unroll
    for (int c=0;c<2;++c) {
      int off = c ? off1 : off0;
      s16x8 af[4], bfr[4];
      #pragma unroll
      for (int mi=0;mi<4;++mi)
        af[mi] = *(const s16x8*)(Alin + (wr*64+mi*16+l16)*64 + off);
      #pragma unroll
      for (int ni=0;ni<4;++ni)
        bfr[ni] = *(const s16x8*)(Blin + (wc*64+ni*16+l16)*64 + off);
      #pragma unroll
      for (int mi=0;mi<4;++mi)
        #pragma unroll
        for (int ni=0;ni<4;++ni)
          acc[mi][ni] = __builtin_amdgcn_mfma_f32_16x16x32_bf16(af[mi], bfr[ni], acc[mi][ni],0,0,0);
    }
  }

  if (mode == 0) {
    int which = n0 >> 10;
    int bb = m0 >> 11, t0 = m0 & 2047;
    if (which < 2) {
      __hip_bfloat16* outp = (which==0)?Qb:Kb;
      #pragma unroll
      for (int mi=0;mi<4;++mi) {
        #pragma unroll
        for (int ni=0;ni<4;++ni) {
          int ncol = (n0 & 1023) + wc*64 + ni*16 + l16;
          int hh = ncol>>6, dd = ncol&63;
          #pragma unroll
          for (int r=0;r<4;++r) {
            int t = t0 + wr*64 + mi*16 + quad*4 + r;
            outp[((size_t)(bb*N_HEADS + hh)*TSEQ + t)*HD + dd] = __float2bfloat16(acc[mi][ni][r]);
          }
        }
      }
    } else {
      // V: transpose 128x128 tile (2 heads) in LDS, store [B,H,d,T]
      int hh0 = (n0 & 1023) >> 6;
      __hip_bfloat16 (*Ts)[136] = (__hip_bfloat16(*)[136])smem;  // 64x136x2=17408
      #pragma unroll
      for (int p=0;p<2;++p) {
        __syncthreads();   // Ts region free (prev frag reads / prev pass stores done)
        if (wc == p) {
          #pragma unroll
          for (int mi=0;mi<4;++mi)
            #pragma unroll
            for (int ni=0;ni<4;++ni) {
              int dd = ni*16 + l16;
              #pragma unroll
              for (int r=0;r<4;++r)
                Ts[dd][wr*64 + mi*16 + quad*4 + r] = __float2bfloat16(acc[mi][ni][r]);
            }
        }
        __syncthreads();
        int dd = tid>>2, tc = (tid&3)*32;
        __hip_bfloat16* dst = Vt + ((size_t)(bb*N_HEADS + hh0 + p)*HD + dd)*TSEQ + t0 + tc;
        #pragma unroll
        for (int c4=0;c4<4;++c4)
          *(uint4*)(dst + c4*8) = *(const uint4*)&Ts[dd][tc + c4*8];
      }
    }
  } else {
    #pragma unroll
    for (int mi=0;mi<4;++mi) {
      #pragma unroll
      for (int ni=0;ni<4;++ni) {
        int col = n0 + wc*64 + ni*16 + l16;
        float bs = bias[col];
        #pragma unroll
        for (int r=0;r<4;++r) {
          int m = m0 + wr*64 + mi*16 + quad*4 + r;
          out[(size_t)m*N_EMBD + col] = acc[mi][ni][r] + bs;
        }
      }
    }
  }
}

// ---- MFMA causal flash attention, 128 queries/block, 32 q/wave ----
// R0: causal load-balance remap (qb reflected on odd bz).
// R1 (this round): DOUBLE-BUFFERED K/V staging with counted vmcnt.
//   Old structure exposed ~600-900cy of global_load_lds latency per tile
//   (stage -> syncthreads(vmcnt0 drain) -> compute): 3400 cyc/block-tile
//   observed vs ~1300 of real work; pipes <50% busy.
//   New: stage(next) issued BEFORE compute(cur); s_waitcnt vmcnt(4) keeps
//   the 4 next-tile loads in flight across the barrier; raw s_barrier
//   (no vmcnt0 drain) + lgkmcnt(0) before the reuse barrier.
//   Hazards: buf[cur^1] staged at iter t is read at t+1 (barrier C);
//   buf[cur] restaged at t+1 only after barrier E with lgkmcnt(0) (all
//   frag reads complete). Ps band is per-wave-private: same-wave ds
//   ordering suffices, no barrier needed.
//   LDS 50176B -> 3 blocks/CU (was 4); 256 blocks backfill, remap keeps
//   resident sets ~balanced (36+2bx resident + long-first backfill).
#define PST 68
__global__ __launch_bounds__(256) void attn_kernel(
    const __hip_bfloat16* __restrict__ Qb, const __hip_bfloat16* __restrict__ Kb,
    const __hip_bfloat16* __restrict__ Vt, __hip_bfloat16* __restrict__ Yb) {
  __shared__ __align__(16) __hip_bfloat16 Ks[2][64][64];   // [buf][key][d] swizzled
  __shared__ __align__(16) __hip_bfloat16 Vs[2][64][64];   // [buf][d][key] swizzled
  __shared__ __align__(16) __hip_bfloat16 Ps[128][PST];    // [q][key]
  int tid = threadIdx.x;
  int b = blockIdx.z, h = blockIdx.y;
  int qb = (b & 1) ? (TSEQ/128 - 1 - blockIdx.x) : blockIdx.x;  // R0 balance remap
  int q0 = qb*128;
  size_t bhT  = (size_t)(b*N_HEADS + h)*TSEQ;
  size_t bhHD = (size_t)(b*N_HEADS + h)*HD;
  int lane = tid&63, w = tid>>6, l16 = lane&15, quad = lane>>4;
  int wq = w*32;                       // wave's query band
  int xg = l16 & 7;
  int off0 = ((quad    ) ^ xg)*8;
  int off1 = ((quad + 4) ^ xg)*8;

  // staging addresses (per-thread, constant across tiles except k0)
  int slot0 = tid,        row0 = slot0>>3, gcA = ((tid&7) ^ (row0&7))*8;
  int slot1 = 256 + tid,  row1 = slot1>>3, gcB = ((tid&7) ^ (row1&7))*8;

  // Q fragments (A-layout) for 2 q-tiles x 2 k-chunks
  s16x8 qf[2][2];
  #pragma unroll
  for (int mi=0;mi<2;++mi) {
    const __hip_bfloat16* qrow = Qb + (bhT + q0 + wq + mi*16 + l16)*HD;
    qf[mi][0] = *(const s16x8*)(qrow + quad*8);
    qf[mi][1] = *(const s16x8*)(qrow + 32 + quad*8);
  }

  f32x4 z4 = {0.f,0.f,0.f,0.f};
  f32x4 oacc[4][2];
  #pragma unroll
  for (int ni=0;ni<4;++ni) { oacc[ni][0]=z4; oacc[ni][1]=z4; }
  float lrow[2][4] = {{0.f,0.f,0.f,0.f},{0.f,0.f,0.f,0.f}};

  int ntiles = 2*qb + 2;

  // prologue: stage tile 0 into buffer 0 (4 glds16 per thread)
  {
    glds16(Kb + (bhT + 0 + row0)*HD + gcA,    &Ks[0][0][0] + slot0*8);
    glds16(Vt + (bhHD + row0)*TSEQ + 0 + gcA, &Vs[0][0][0] + slot0*8);
    glds16(Kb + (bhT + 0 + row1)*HD + gcB,    &Ks[0][0][0] + slot1*8);
    glds16(Vt + (bhHD + row1)*TSEQ + 0 + gcB, &Vs[0][0][0] + slot1*8);
  }

  for (int t=0; t<ntiles; ++t) {
    int cur = t&1;
    int k0 = t*64;
    // A: issue next tile's staging into the other buffer
    if (t+1 < ntiles) {
      int kn = k0 + 64;
      glds16(Kb + (bhT + kn + row0)*HD + gcA,     &Ks[cur^1][0][0] + slot0*8);
      glds16(Vt + (bhHD + row0)*TSEQ + kn + gcA,  &Vs[cur^1][0][0] + slot0*8);
      glds16(Kb + (bhT + kn + row1)*HD + gcB,     &Ks[cur^1][0][0] + slot1*8);
      glds16(Vt + (bhHD + row1)*TSEQ + kn + gcB,  &Vs[cur^1][0][0] + slot1*8);
      // B: wait for current tile's 4 loads (oldest); keep the 4 newest in flight
      asm volatile("s_waitcnt vmcnt(4)" ::: "memory");
    } else {
      asm volatile("s_waitcnt vmcnt(0)" ::: "memory");
    }
    // C: all waves' cur-buffer loads landed
    __builtin_amdgcn_s_barrier();
    __builtin_amdgcn_sched_barrier(0);

    const __hip_bfloat16* Kc = &Ks[cur][0][0];
    const __hip_bfloat16* Vc = &Vs[cur][0][0];

    // S = Q K^T : 32q x 64key per wave
    f32x4 sacc[4][2];
    #pragma unroll
    for (int ni=0; ni<4; ++ni) {
      s16x8 kb0 = *(const s16x8*)(Kc + (ni*16+l16)*64 + off0);
      s16x8 kb1 = *(const s16x8*)(Kc + (ni*16+l16)*64 + off1);
      #pragma unroll
      for (int mi=0; mi<2; ++mi) {
        f32x4 s = z4;
        s = __builtin_amdgcn_mfma_f32_16x16x32_bf16(qf[mi][0], kb0, s,0,0,0);
        s = __builtin_amdgcn_mfma_f32_16x16x32_bf16(qf[mi][1], kb1, s,0,0,0);
        sacc[ni][mi] = s;
      }
    }

    // mask + exp; accumulate l; P -> LDS (own band; same-wave lgkmcnt ordering)
    // wave-uniform: min query row of this wave = q0+wq; max key col = k0+63.
    if (q0 + wq >= k0 + 63) {
      // fully unmasked tile for this wave: no compare needed
      #pragma unroll
      for (int ni=0; ni<4; ++ni) {
        #pragma unroll
        for (int mi=0; mi<2; ++mi) {
          #pragma unroll
          for (int r=0; r<4; ++r) {
            float p = __expf(sacc[ni][mi][r]*0.125f);
            lrow[mi][r] += p;
            Ps[wq + mi*16 + quad*4 + r][ni*16 + l16] = __float2bfloat16(p);
          }
        }
      }
    } else {
      #pragma unroll
      for (int ni=0; ni<4; ++ni) {
        int kcol = k0 + ni*16 + l16;
        #pragma unroll
        for (int mi=0; mi<2; ++mi) {
          int qrb = q0 + wq + mi*16 + quad*4;
          #pragma unroll
          for (int r=0; r<4; ++r) {
            float p = (qrb + r >= kcol) ? __expf(sacc[ni][mi][r]*0.125f) : 0.f;
            lrow[mi][r] += p;
            Ps[wq + mi*16 + quad*4 + r][ni*16 + l16] = __float2bfloat16(p);
          }
        }
      }
    }

    // O += P V
    union U8 { s16x8 v; uint2 u[2]; };
    U8 aP[2][2];
    #pragma unroll
    for (int mi=0; mi<2; ++mi)
      #pragma unroll
      for (int c=0; c<2; ++c) {
        const __hip_bfloat16* pr = &Ps[wq + mi*16 + l16][c*32 + quad*8];
        aP[mi][c].u[0] = *(const uint2*)pr;
        aP[mi][c].u[1] = *(const uint2*)(pr + 4);
      }
    #pragma unroll
    for (int ni=0; ni<4; ++ni) {
      s16x8 vb0 = *(const s16x8*)(Vc + (ni*16+l16)*64 + off0);
      s16x8 vb1 = *(const s16x8*)(Vc + (ni*16+l16)*64 + off1);
      #pragma unroll
      for (int mi=0; mi<2; ++mi) {
        oacc[ni][mi] = __builtin_amdgcn_mfma_f32_16x16x32_bf16(aP[mi][0].v, vb0, oacc[ni][mi],0,0,0);
        oacc[ni][mi] = __builtin_amdgcn_mfma_f32_16x16x32_bf16(aP[mi][1].v, vb1, oacc[ni][mi],0,0,0);
      }
    }

    // E: all frag reads of buf[cur] complete -> safe to restage it next iter
    asm volatile("s_waitcnt lgkmcnt(0)" ::: "memory");
    __builtin_amdgcn_s_barrier();
    __builtin_amdgcn_sched_barrier(0);
  }

  // reduce l across the 16 lanes of each quad-row group
  #pragma unroll
  for (int off=1; off<16; off<<=1)
    #pragma unroll
    for (int mi=0; mi<2; ++mi)
      #pragma unroll
      for (int r=0; r<4; ++r) lrow[mi][r] += __shfl_xor(lrow[mi][r], off);

  #pragma unroll
  for (int mi=0; mi<2; ++mi)
    #pragma unroll
    for (int r=0; r<4; ++r) {
      float inv = 1.f / lrow[mi][r];
      int tq = q0 + wq + mi*16 + quad*4 + r;
      __hip_bfloat16* yr = Yb + ((size_t)(b*TSEQ + tq))*N_EMBD + h*HD;
      #pragma unroll
      for (int ni=0; ni<4; ++ni)
        yr[ni*16 + l16] = __float2bfloat16(oacc[ni][mi][r] * inv);
    }
}

extern "C" void kernel_launch(void* const* d_in, const int* in_sizes, int n_in,
                              void* d_out, int out_size, void* d_ws, size_t ws_size,
                              hipStream_t stream) {
  const float* x  = (const float*)d_in[0];
  const float* Wq = (const float*)d_in[1];
  const float* Wk = (const float*)d_in[2];
  const float* Wv = (const float*)d_in[3];
  const float* Wp = (const float*)d_in[4];
  const float* bp = (const float*)d_in[5];

  char* w = (char*)d_ws;
  __hip_bfloat16* xb    = (__hip_bfloat16*)w;  w += (size_t)M_TOT*N_EMBD*2;   // 16 MB
  __hip_bfloat16* wqkvt = (__hip_bfloat16*)w;  w += (size_t)3*N_EMBD*N_EMBD*2;// 6 MB
  __hip_bfloat16* wpt   = (__hip_bfloat16*)w;  w += (size_t)N_EMBD*N_EMBD*2;  // 2 MB
  __hip_bfloat16* Qb    = (__hip_bfloat16*)w;  w += (size_t)M_TOT*N_EMBD*2;   // 16 MB
  __hip_bfloat16* Kb    = (__hip_bfloat16*)w;  w += (size_t)M_TOT*N_EMBD*2;   // 16 MB
  __hip_bfloat16* Vt    = (__hip_bfloat16*)w;  w += (size_t)M_TOT*N_EMBD*2;   // 16 MB [B,H,d,T]
  __hip_bfloat16* Yb    = (__hip_bfloat16*)w;                                  // 16 MB (88 MB total)

  xcast_kernel<<<dim3(M_TOT*N_EMBD/1024), dim3(256), 0, stream>>>(x, xb);
  wcast_kernel<<<dim3(32,32,4), dim3(32,8), 0, stream>>>(Wq,Wk,Wv,Wp,wqkvt,wpt);
  gemm_kernel<<<dim3(24,64), dim3(256), 0, stream>>>(xb, wqkvt, Qb,Kb,Vt, nullptr, nullptr, 0);
  attn_kernel<<<dim3(TSEQ/128,N_HEADS,BATCH), dim3(256), 0, stream>>>(Qb,Kb,Vt,Yb);
  gemm_kernel<<<dim3(8,64), dim3(256), 0, stream>>>(Yb, wpt, nullptr,nullptr,nullptr,
                                                    (float*)d_out, bp, 1);
}

// Round 3
// 278.132 us; speedup vs baseline: 1.1379x; 1.0009x over previous
//
#include <hip/hip_runtime.h>
#include <hip/hip_bf16.h>

#define N_EMBD 1024
#define N_HEADS 16
#define HD 64
#define TSEQ 2048
#define BATCH 4
#define M_TOT (BATCH*TSEQ)   // 8192

typedef short s16x8 __attribute__((ext_vector_type(8)));
typedef float f32x4 __attribute__((ext_vector_type(4)));

__device__ __forceinline__ void glds16(const void* g, void* l) {
  __builtin_amdgcn_global_load_lds((const __attribute__((address_space(1))) void*)g,
                                   (__attribute__((address_space(3))) void*)l, 16, 0, 0);
}

// exp(s*0.125) = 2^(s * 0.125*log2(e)) via a single hardware v_exp_f32.
// R2: __expf was suspected to lower to the precise ocml exp (~15 VALU ops);
// VALUBusy accounting showed ~1215 VALU-cyc/wave-tile vs ~300 hand-counted.
// s_nop 0 inside the asm covers the trans-op->VALU-consumer wait state
// (hazard recognizer can't see into inline asm).
__device__ __forceinline__ float exp_scaled(float s) {
  float r;
  asm("v_exp_f32 %0, %1\n\ts_nop 0" : "=v"(r) : "v"(s * 0.18033688011112042f));
  return r;
}

// ---- cast x fp32 -> bf16, 4 elems/thread ----
__global__ __launch_bounds__(256) void xcast_kernel(const float* __restrict__ x,
                                                    __hip_bfloat16* __restrict__ xb) {
  int i = blockIdx.x * 256 + threadIdx.x;
  float4 f = ((const float4*)x)[i];
  __hip_bfloat162 p0, p1;
  p0.x = __float2bfloat16(f.x); p0.y = __float2bfloat16(f.y);
  p1.x = __float2bfloat16(f.z); p1.y = __float2bfloat16(f.w);
  ((__hip_bfloat162*)xb)[2*i]   = p0;
  ((__hip_bfloat162*)xb)[2*i+1] = p1;
}

// ---- transpose + cast weights: out[n][c] = in[c][n], bf16 ----
__global__ void wcast_kernel(const float* __restrict__ Wq, const float* __restrict__ Wk,
                             const float* __restrict__ Wv, const float* __restrict__ Wp,
                             __hip_bfloat16* __restrict__ wqkvt, __hip_bfloat16* __restrict__ wpt) {
  __shared__ float tile[32][33];
  int z = blockIdx.z;
  const float* in = (z==0)?Wq:(z==1)?Wk:(z==2)?Wv:Wp;
  __hip_bfloat16* out = (z<3) ? (wqkvt + (size_t)z*N_EMBD*N_EMBD) : wpt;
  int tx = threadIdx.x, ty = threadIdx.y;
  int x  = blockIdx.x*32 + tx;
  int y0 = blockIdx.y*32;
  #pragma unroll
  for (int j=0;j<4;++j) tile[ty + j*8][tx] = in[(size_t)(y0+ty+j*8)*N_EMBD + x];
  __syncthreads();
  int xo  = y0 + tx;
  int yo0 = blockIdx.x*32;
  #pragma unroll
  for (int j=0;j<4;++j)
    out[(size_t)(yo0+ty+j*8)*N_EMBD + xo] = __float2bfloat16(tile[tx][ty+j*8]);
}

// ---- bf16 MFMA GEMM, m97-style: 128x128 tile, BK=64, glds16 staging ----
// LDS layout is XOR-swizzled on the GLOBAL fetch side: physical 16B-group g
// holds logical group g^(row&7)  (glds LDS side must stay linear lane*16).
// mode 0: N=3072 (QKV). Q,K scatter [B,H,T,d]; V stored TRANSPOSED [B,H,d,T].
// mode 1: N=1024 (proj), out fp32 = acc + bias.
__global__ __launch_bounds__(256) void gemm_kernel(
    const __hip_bfloat16* __restrict__ A,   // [M][1024] bf16
    const __hip_bfloat16* __restrict__ Bt,  // [N][1024] bf16 (transposed weight)
    __hip_bfloat16* __restrict__ Qb, __hip_bfloat16* __restrict__ Kb,
    __hip_bfloat16* __restrict__ Vt,        // [B,H,d,T]
    float* __restrict__ out, const float* __restrict__ bias, int mode) {
  __shared__ __align__(16) char smem[32768];
  __hip_bfloat16* Alin = (__hip_bfloat16*)smem;            // 128x64
  __hip_bfloat16* Blin = (__hip_bfloat16*)(smem + 16384);  // 128x64
  int tid = threadIdx.x;
  int m0 = blockIdx.y*128, n0 = blockIdx.x*128;
  int w = tid>>6, lane = tid&63, l16 = lane&15, quad = lane>>4;
  int wr = w>>1, wc = w&1;
  int xg = l16 & 7;
  int off0 = ((quad    ) ^ xg)*8;   // physical col offset for logical k-chunk 0
  int off1 = ((quad + 4) ^ xg)*8;   // logical group c*4+quad, c=1
  f32x4 acc[4][4];
  #pragma unroll
  for (int mi=0;mi<4;++mi)
    #pragma unroll
    for (int ni=0;ni<4;++ni) acc[mi][ni] = (f32x4){0.f,0.f,0.f,0.f};

  for (int k0=0; k0<N_EMBD; k0+=64) {
    __syncthreads();   // prev frag reads done before restaging
    #pragma unroll
    for (int rd=0; rd<4; ++rd) {
      int slot = rd*256 + tid;
      int row  = slot>>3;
      int gc8  = ((tid&7) ^ (row&7))*8;
      glds16(A  + (size_t)(m0+row)*N_EMBD + k0 + gc8, Alin + slot*8);
      glds16(Bt + (size_t)(n0+row)*N_EMBD + k0 + gc8, Blin + slot*8);
    }
    __syncthreads();   // drain vmcnt
    #pragma unroll
    for (int c=0;c<2;++c) {
      int off = c ? off1 : off0;
      s16x8 af[4], bfr[4];
      #pragma unroll
      for (int mi=0;mi<4;++mi)
        af[mi] = *(const s16x8*)(Alin + (wr*64+mi*16+l16)*64 + off);
      #pragma unroll
      for (int ni=0;ni<4;++ni)
        bfr[ni] = *(const s16x8*)(Blin + (wc*64+ni*16+l16)*64 + off);
      #pragma unroll
      for (int mi=0;mi<4;++mi)
        #pragma unroll
        for (int ni=0;ni<4;++ni)
          acc[mi][ni] = __builtin_amdgcn_mfma_f32_16x16x32_bf16(af[mi], bfr[ni], acc[mi][ni],0,0,0);
    }
  }

  if (mode == 0) {
    int which = n0 >> 10;
    int bb = m0 >> 11, t0 = m0 & 2047;
    if (which < 2) {
      __hip_bfloat16* outp = (which==0)?Qb:Kb;
      #pragma unroll
      for (int mi=0;mi<4;++mi) {
        #pragma unroll
        for (int ni=0;ni<4;++ni) {
          int ncol = (n0 & 1023) + wc*64 + ni*16 + l16;
          int hh = ncol>>6, dd = ncol&63;
          #pragma unroll
          for (int r=0;r<4;++r) {
            int t = t0 + wr*64 + mi*16 + quad*4 + r;
            outp[((size_t)(bb*N_HEADS + hh)*TSEQ + t)*HD + dd] = __float2bfloat16(acc[mi][ni][r]);
          }
        }
      }
    } else {
      // V: transpose 128x128 tile (2 heads) in LDS, store [B,H,d,T]
      int hh0 = (n0 & 1023) >> 6;
      __hip_bfloat16 (*Ts)[136] = (__hip_bfloat16(*)[136])smem;  // 64x136x2=17408
      #pragma unroll
      for (int p=0;p<2;++p) {
        __syncthreads();   // Ts region free (prev frag reads / prev pass stores done)
        if (wc == p) {
          #pragma unroll
          for (int mi=0;mi<4;++mi)
            #pragma unroll
            for (int ni=0;ni<4;++ni) {
              int dd = ni*16 + l16;
              #pragma unroll
              for (int r=0;r<4;++r)
                Ts[dd][wr*64 + mi*16 + quad*4 + r] = __float2bfloat16(acc[mi][ni][r]);
            }
        }
        __syncthreads();
        int dd = tid>>2, tc = (tid&3)*32;
        __hip_bfloat16* dst = Vt + ((size_t)(bb*N_HEADS + hh0 + p)*HD + dd)*TSEQ + t0 + tc;
        #pragma unroll
        for (int c4=0;c4<4;++c4)
          *(uint4*)(dst + c4*8) = *(const uint4*)&Ts[dd][tc + c4*8];
      }
    }
  } else {
    #pragma unroll
    for (int mi=0;mi<4;++mi) {
      #pragma unroll
      for (int ni=0;ni<4;++ni) {
        int col = n0 + wc*64 + ni*16 + l16;
        float bs = bias[col];
        #pragma unroll
        for (int r=0;r<4;++r) {
          int m = m0 + wr*64 + mi*16 + quad*4 + r;
          out[(size_t)m*N_EMBD + col] = acc[mi][ni][r] + bs;
        }
      }
    }
  }
}

// ---- MFMA causal flash attention, 128 queries/block, 32 q/wave ----
// R0: causal load-balance remap (qb reflected on odd bz): 137 -> 96us.
// R1: double-buffered K/V + counted vmcnt: NULL (96 -> 98us) -- implicit
//     wave overlap already hid the glds latency (Common-mistake #5).
//     Kept anyway (harmless, helps straggler blocks).
// R2 (this round): hardware exp. VALUBusy accounting: 82.6k VALU-cyc/SIMD
//     over 68 wave-tiles = 1215 cyc/wave-tile vs ~300 hand-counted -> the
//     4x gap is __expf lowering to precise ocml exp (~15 VALU ops/elem).
//     Replace with raw v_exp_f32, scale folded: exp(s/8)=2^(s*0.18034).
#define PST 68
__global__ __launch_bounds__(256) void attn_kernel(
    const __hip_bfloat16* __restrict__ Qb, const __hip_bfloat16* __restrict__ Kb,
    const __hip_bfloat16* __restrict__ Vt, __hip_bfloat16* __restrict__ Yb) {
  __shared__ __align__(16) __hip_bfloat16 Ks[2][64][64];   // [buf][key][d] swizzled
  __shared__ __align__(16) __hip_bfloat16 Vs[2][64][64];   // [buf][d][key] swizzled
  __shared__ __align__(16) __hip_bfloat16 Ps[128][PST];    // [q][key]
  int tid = threadIdx.x;
  int b = blockIdx.z, h = blockIdx.y;
  int qb = (b & 1) ? (TSEQ/128 - 1 - blockIdx.x) : blockIdx.x;  // R0 balance remap
  int q0 = qb*128;
  size_t bhT  = (size_t)(b*N_HEADS + h)*TSEQ;
  size_t bhHD = (size_t)(b*N_HEADS + h)*HD;
  int lane = tid&63, w = tid>>6, l16 = lane&15, quad = lane>>4;
  int wq = w*32;                       // wave's query band
  int xg = l16 & 7;
  int off0 = ((quad    ) ^ xg)*8;
  int off1 = ((quad + 4) ^ xg)*8;

  // staging addresses (per-thread, constant across tiles except k0)
  int slot0 = tid,        row0 = slot0>>3, gcA = ((tid&7) ^ (row0&7))*8;
  int slot1 = 256 + tid,  row1 = slot1>>3, gcB = ((tid&7) ^ (row1&7))*8;

  // Q fragments (A-layout) for 2 q-tiles x 2 k-chunks
  s16x8 qf[2][2];
  #pragma unroll
  for (int mi=0;mi<2;++mi) {
    const __hip_bfloat16* qrow = Qb + (bhT + q0 + wq + mi*16 + l16)*HD;
    qf[mi][0] = *(const s16x8*)(qrow + quad*8);
    qf[mi][1] = *(const s16x8*)(qrow + 32 + quad*8);
  }

  f32x4 z4 = {0.f,0.f,0.f,0.f};
  f32x4 oacc[4][2];
  #pragma unroll
  for (int ni=0;ni<4;++ni) { oacc[ni][0]=z4; oacc[ni][1]=z4; }
  float lrow[2][4] = {{0.f,0.f,0.f,0.f},{0.f,0.f,0.f,0.f}};

  int ntiles = 2*qb + 2;

  // prologue: stage tile 0 into buffer 0 (4 glds16 per thread)
  {
    glds16(Kb + (bhT + 0 + row0)*HD + gcA,    &Ks[0][0][0] + slot0*8);
    glds16(Vt + (bhHD + row0)*TSEQ + 0 + gcA, &Vs[0][0][0] + slot0*8);
    glds16(Kb + (bhT + 0 + row1)*HD + gcB,    &Ks[0][0][0] + slot1*8);
    glds16(Vt + (bhHD + row1)*TSEQ + 0 + gcB, &Vs[0][0][0] + slot1*8);
  }

  for (int t=0; t<ntiles; ++t) {
    int cur = t&1;
    int k0 = t*64;
    // A: issue next tile's staging into the other buffer
    if (t+1 < ntiles) {
      int kn = k0 + 64;
      glds16(Kb + (bhT + kn + row0)*HD + gcA,     &Ks[cur^1][0][0] + slot0*8);
      glds16(Vt + (bhHD + row0)*TSEQ + kn + gcA,  &Vs[cur^1][0][0] + slot0*8);
      glds16(Kb + (bhT + kn + row1)*HD + gcB,     &Ks[cur^1][0][0] + slot1*8);
      glds16(Vt + (bhHD + row1)*TSEQ + kn + gcB,  &Vs[cur^1][0][0] + slot1*8);
      // B: wait for current tile's 4 loads (oldest); keep the 4 newest in flight
      asm volatile("s_waitcnt vmcnt(4)" ::: "memory");
    } else {
      asm volatile("s_waitcnt vmcnt(0)" ::: "memory");
    }
    // C: all waves' cur-buffer loads landed
    __builtin_amdgcn_s_barrier();
    __builtin_amdgcn_sched_barrier(0);

    const __hip_bfloat16* Kc = &Ks[cur][0][0];
    const __hip_bfloat16* Vc = &Vs[cur][0][0];

    // S = Q K^T : 32q x 64key per wave
    f32x4 sacc[4][2];
    #pragma unroll
    for (int ni=0; ni<4; ++ni) {
      s16x8 kb0 = *(const s16x8*)(Kc + (ni*16+l16)*64 + off0);
      s16x8 kb1 = *(const s16x8*)(Kc + (ni*16+l16)*64 + off1);
      #pragma unroll
      for (int mi=0; mi<2; ++mi) {
        f32x4 s = z4;
        s = __builtin_amdgcn_mfma_f32_16x16x32_bf16(qf[mi][0], kb0, s,0,0,0);
        s = __builtin_amdgcn_mfma_f32_16x16x32_bf16(qf[mi][1], kb1, s,0,0,0);
        sacc[ni][mi] = s;
      }
    }

    // mask + exp; accumulate l; P -> LDS (own band; same-wave lgkmcnt ordering)
    // wave-uniform: min query row of this wave = q0+wq; max key col = k0+63.
    if (q0 + wq >= k0 + 63) {
      // fully unmasked tile for this wave: no compare needed
      #pragma unroll
      for (int ni=0; ni<4; ++ni) {
        #pragma unroll
        for (int mi=0; mi<2; ++mi) {
          #pragma unroll
          for (int r=0; r<4; ++r) {
            float p = exp_scaled(sacc[ni][mi][r]);
            lrow[mi][r] += p;
            Ps[wq + mi*16 + quad*4 + r][ni*16 + l16] = __float2bfloat16(p);
          }
        }
      }
    } else {
      #pragma unroll
      for (int ni=0; ni<4; ++ni) {
        int kcol = k0 + ni*16 + l16;
        #pragma unroll
        for (int mi=0; mi<2; ++mi) {
          int qrb = q0 + wq + mi*16 + quad*4;
          #pragma unroll
          for (int r=0; r<4; ++r) {
            float e = exp_scaled(sacc[ni][mi][r]);
            float p = (qrb + r >= kcol) ? e : 0.f;
            lrow[mi][r] += p;
            Ps[wq + mi*16 + quad*4 + r][ni*16 + l16] = __float2bfloat16(p);
          }
        }
      }
    }

    // O += P V
    union U8 { s16x8 v; uint2 u[2]; };
    U8 aP[2][2];
    #pragma unroll
    for (int mi=0; mi<2; ++mi)
      #pragma unroll
      for (int c=0; c<2; ++c) {
        const __hip_bfloat16* pr = &Ps[wq + mi*16 + l16][c*32 + quad*8];
        aP[mi][c].u[0] = *(const uint2*)pr;
        aP[mi][c].u[1] = *(const uint2*)(pr + 4);
      }
    #pragma unroll
    for (int ni=0; ni<4; ++ni) {
      s16x8 vb0 = *(const s16x8*)(Vc + (ni*16+l16)*64 + off0);
      s16x8 vb1 = *(const s16x8*)(Vc + (ni*16+l16)*64 + off1);
      #pragma unroll
      for (int mi=0; mi<2; ++mi) {
        oacc[ni][mi] = __builtin_amdgcn_mfma_f32_16x16x32_bf16(aP[mi][0].v, vb0, oacc[ni][mi],0,0,0);
        oacc[ni][mi] = __builtin_amdgcn_mfma_f32_16x16x32_bf16(aP[mi][1].v, vb1, oacc[ni][mi],0,0,0);
      }
    }

    // E: all frag reads of buf[cur] complete -> safe to restage it next iter
    asm volatile("s_waitcnt lgkmcnt(0)" ::: "memory");
    __builtin_amdgcn_s_barrier();
    __builtin_amdgcn_sched_barrier(0);
  }

  // reduce l across the 16 lanes of each quad-row group
  #pragma unroll
  for (int off=1; off<16; off<<=1)
    #pragma unroll
    for (int mi=0; mi<2; ++mi)
      #pragma unroll
      for (int r=0; r<4; ++r) lrow[mi][r] += __shfl_xor(lrow[mi][r], off);

  #pragma unroll
  for (int mi=0; mi<2; ++mi)
    #pragma unroll
    for (int r=0; r<4; ++r) {
      float inv = 1.f / lrow[mi][r];
      int tq = q0 + wq + mi*16 + quad*4 + r;
      __hip_bfloat16* yr = Yb + ((size_t)(b*TSEQ + tq))*N_EMBD + h*HD;
      #pragma unroll
      for (int ni=0; ni<4; ++ni)
        yr[ni*16 + l16] = __float2bfloat16(oacc[ni][mi][r] * inv);
    }
}

extern "C" void kernel_launch(void* const* d_in, const int* in_sizes, int n_in,
                              void* d_out, int out_size, void* d_ws, size_t ws_size,
                              hipStream_t stream) {
  const float* x  = (const float*)d_in[0];
  const float* Wq = (const float*)d_in[1];
  const float* Wk = (const float*)d_in[2];
  const float* Wv = (const float*)d_in[3];
  const float* Wp = (const float*)d_in[4];
  const float* bp = (const float*)d_in[5];

  char* w = (char*)d_ws;
  __hip_bfloat16* xb    = (__hip_bfloat16*)w;  w += (size_t)M_TOT*N_EMBD*2;   // 16 MB
  __hip_bfloat16* wqkvt = (__hip_bfloat16*)w;  w += (size_t)3*N_EMBD*N_EMBD*2;// 6 MB
  __hip_bfloat16* wpt   = (__hip_bfloat16*)w;  w += (size_t)N_EMBD*N_EMBD*2;  // 2 MB
  __hip_bfloat16* Qb    = (__hip_bfloat16*)w;  w += (size_t)M_TOT*N_EMBD*2;   // 16 MB
  __hip_bfloat16* Kb    = (__hip_bfloat16*)w;  w += (size_t)M_TOT*N_EMBD*2;   // 16 MB
  __hip_bfloat16* Vt    = (__hip_bfloat16*)w;  w += (size_t)M_TOT*N_EMBD*2;   // 16 MB [B,H,d,T]
  __hip_bfloat16* Yb    = (__hip_bfloat16*)w;                                  // 16 MB (88 MB total)

  xcast_kernel<<<dim3(M_TOT*N_EMBD/1024), dim3(256), 0, stream>>>(x, xb);
  wcast_kernel<<<dim3(32,32,4), dim3(32,8), 0, stream>>>(Wq,Wk,Wv,Wp,wqkvt,wpt);
  gemm_kernel<<<dim3(24,64), dim3(256), 0, stream>>>(xb, wqkvt, Qb,Kb,Vt, nullptr, nullptr, 0);
  attn_kernel<<<dim3(TSEQ/128,N_HEADS,BATCH), dim3(256), 0, stream>>>(Qb,Kb,Vt,Yb);
  gemm_kernel<<<dim3(8,64), dim3(256), 0, stream>>>(Yb, wpt, nullptr,nullptr,nullptr,
                                                    (float*)d_out, bp, 1);
}

// Round 4
// 270.822 us; speedup vs baseline: 1.1686x; 1.0270x over previous
//
#include <hip/hip_runtime.h>
#include <hip/hip_bf16.h>

#define N_EMBD 1024
#define N_HEADS 16
#define HD 64
#define TSEQ 2048
#define BATCH 4
#define M_TOT (BATCH*TSEQ)   // 8192

typedef short s16x8 __attribute__((ext_vector_type(8)));
typedef float f32x4 __attribute__((ext_vector_type(4)));

__device__ __forceinline__ void glds16(const void* g, void* l) {
  __builtin_amdgcn_global_load_lds((const __attribute__((address_space(1))) void*)g,
                                   (__attribute__((address_space(3))) void*)l, 16, 0, 0);
}

// exp(s*0.125) = 2^(s * 0.125*log2(e)) via a single hardware v_exp_f32 (R2).
__device__ __forceinline__ float exp_scaled(float s) {
  float r;
  asm("v_exp_f32 %0, %1\n\ts_nop 0" : "=v"(r) : "v"(s * 0.18033688011112042f));
  return r;
}

// pack two f32 -> bf16x2 (src0 in low 16). No builtin on gfx950 (T12/m240).
__device__ __forceinline__ unsigned cvtpk(float lo, float hi) {
  unsigned r;
  asm("v_cvt_pk_bf16_f32 %0, %1, %2" : "=v"(r) : "v"(lo), "v"(hi));
  return r;
}

// ---- cast x fp32 -> bf16, 4 elems/thread ----
__global__ __launch_bounds__(256) void xcast_kernel(const float* __restrict__ x,
                                                    __hip_bfloat16* __restrict__ xb) {
  int i = blockIdx.x * 256 + threadIdx.x;
  float4 f = ((const float4*)x)[i];
  __hip_bfloat162 p0, p1;
  p0.x = __float2bfloat16(f.x); p0.y = __float2bfloat16(f.y);
  p1.x = __float2bfloat16(f.z); p1.y = __float2bfloat16(f.w);
  ((__hip_bfloat162*)xb)[2*i]   = p0;
  ((__hip_bfloat162*)xb)[2*i+1] = p1;
}

// ---- transpose + cast weights: out[n][c] = in[c][n], bf16 ----
__global__ void wcast_kernel(const float* __restrict__ Wq, const float* __restrict__ Wk,
                             const float* __restrict__ Wv, const float* __restrict__ Wp,
                             __hip_bfloat16* __restrict__ wqkvt, __hip_bfloat16* __restrict__ wpt) {
  __shared__ float tile[32][33];
  int z = blockIdx.z;
  const float* in = (z==0)?Wq:(z==1)?Wk:(z==2)?Wv:Wp;
  __hip_bfloat16* out = (z<3) ? (wqkvt + (size_t)z*N_EMBD*N_EMBD) : wpt;
  int tx = threadIdx.x, ty = threadIdx.y;
  int x  = blockIdx.x*32 + tx;
  int y0 = blockIdx.y*32;
  #pragma unroll
  for (int j=0;j<4;++j) tile[ty + j*8][tx] = in[(size_t)(y0+ty+j*8)*N_EMBD + x];
  __syncthreads();
  int xo  = y0 + tx;
  int yo0 = blockIdx.x*32;
  #pragma unroll
  for (int j=0;j<4;++j)
    out[(size_t)(yo0+ty+j*8)*N_EMBD + xo] = __float2bfloat16(tile[tx][ty+j*8]);
}

// ---- bf16 MFMA GEMM, m97-style: 128x128 tile, BK=64, glds16 staging ----
// LDS layout is XOR-swizzled on the GLOBAL fetch side: physical 16B-group g
// holds logical group g^(row&7)  (glds LDS side must stay linear lane*16).
// mode 0: N=3072 (QKV). Q,K scatter [B,H,T,d]; V stored TRANSPOSED [B,H,d,T].
// mode 1: N=1024 (proj), out fp32 = acc + bias.
__global__ __launch_bounds__(256) void gemm_kernel(
    const __hip_bfloat16* __restrict__ A,   // [M][1024] bf16
    const __hip_bfloat16* __restrict__ Bt,  // [N][1024] bf16 (transposed weight)
    __hip_bfloat16* __restrict__ Qb, __hip_bfloat16* __restrict__ Kb,
    __hip_bfloat16* __restrict__ Vt,        // [B,H,d,T]
    float* __restrict__ out, const float* __restrict__ bias, int mode) {
  __shared__ __align__(16) char smem[32768];
  __hip_bfloat16* Alin = (__hip_bfloat16*)smem;            // 128x64
  __hip_bfloat16* Blin = (__hip_bfloat16*)(smem + 16384);  // 128x64
  int tid = threadIdx.x;
  int m0 = blockIdx.y*128, n0 = blockIdx.x*128;
  int w = tid>>6, lane = tid&63, l16 = lane&15, quad = lane>>4;
  int wr = w>>1, wc = w&1;
  int xg = l16 & 7;
  int off0 = ((quad    ) ^ xg)*8;   // physical col offset for logical k-chunk 0
  int off1 = ((quad + 4) ^ xg)*8;   // logical group c*4+quad, c=1
  f32x4 acc[4][4];
  #pragma unroll
  for (int mi=0;mi<4;++mi)
    #pragma unroll
    for (int ni=0;ni<4;++ni) acc[mi][ni] = (f32x4){0.f,0.f,0.f,0.f};

  for (int k0=0; k0<N_EMBD; k0+=64) {
    __syncthreads();   // prev frag reads done before restaging
    #pragma unroll
    for (int rd=0; rd<4; ++rd) {
      int slot = rd*256 + tid;
      int row  = slot>>3;
      int gc8  = ((tid&7) ^ (row&7))*8;
      glds16(A  + (size_t)(m0+row)*N_EMBD + k0 + gc8, Alin + slot*8);
      glds16(Bt + (size_t)(n0+row)*N_EMBD + k0 + gc8, Blin + slot*8);
    }
    __syncthreads();   // drain vmcnt
    #pragma unroll
    for (int c=0;c<2;++c) {
      int off = c ? off1 : off0;
      s16x8 af[4], bfr[4];
      #pragma unroll
      for (int mi=0;mi<4;++mi)
        af[mi] = *(const s16x8*)(Alin + (wr*64+mi*16+l16)*64 + off);
      #pragma unroll
      for (int ni=0;ni<4;++ni)
        bfr[ni] = *(const s16x8*)(Blin + (wc*64+ni*16+l16)*64 + off);
      #pragma unroll
      for (int mi=0;mi<4;++mi)
        #pragma unroll
        for (int ni=0;ni<4;++ni)
          acc[mi][ni] = __builtin_amdgcn_mfma_f32_16x16x32_bf16(af[mi], bfr[ni], acc[mi][ni],0,0,0);
    }
  }

  if (mode == 0) {
    int which = n0 >> 10;
    int bb = m0 >> 11, t0 = m0 & 2047;
    if (which < 2) {
      __hip_bfloat16* outp = (which==0)?Qb:Kb;
      #pragma unroll
      for (int mi=0;mi<4;++mi) {
        #pragma unroll
        for (int ni=0;ni<4;++ni) {
          int ncol = (n0 & 1023) + wc*64 + ni*16 + l16;
          int hh = ncol>>6, dd = ncol&63;
          #pragma unroll
          for (int r=0;r<4;++r) {
            int t = t0 + wr*64 + mi*16 + quad*4 + r;
            outp[((size_t)(bb*N_HEADS + hh)*TSEQ + t)*HD + dd] = __float2bfloat16(acc[mi][ni][r]);
          }
        }
      }
    } else {
      // V: transpose 128x128 tile (2 heads) in LDS, store [B,H,d,T]
      int hh0 = (n0 & 1023) >> 6;
      __hip_bfloat16 (*Ts)[136] = (__hip_bfloat16(*)[136])smem;  // 64x136x2=17408
      #pragma unroll
      for (int p=0;p<2;++p) {
        __syncthreads();   // Ts region free (prev frag reads / prev pass stores done)
        if (wc == p) {
          #pragma unroll
          for (int mi=0;mi<4;++mi)
            #pragma unroll
            for (int ni=0;ni<4;++ni) {
              int dd = ni*16 + l16;
              #pragma unroll
              for (int r=0;r<4;++r)
                Ts[dd][wr*64 + mi*16 + quad*4 + r] = __float2bfloat16(acc[mi][ni][r]);
            }
        }
        __syncthreads();
        int dd = tid>>2, tc = (tid&3)*32;
        __hip_bfloat16* dst = Vt + ((size_t)(bb*N_HEADS + hh0 + p)*HD + dd)*TSEQ + t0 + tc;
        #pragma unroll
        for (int c4=0;c4<4;++c4)
          *(uint4*)(dst + c4*8) = *(const uint4*)&Ts[dd][tc + c4*8];
      }
    }
  } else {
    #pragma unroll
    for (int mi=0;mi<4;++mi) {
      #pragma unroll
      for (int ni=0;ni<4;++ni) {
        int col = n0 + wc*64 + ni*16 + l16;
        float bs = bias[col];
        #pragma unroll
        for (int r=0;r<4;++r) {
          int m = m0 + wr*64 + mi*16 + quad*4 + r;
          out[(size_t)m*N_EMBD + col] = acc[mi][ni][r] + bs;
        }
      }
    }
  }
}

// ---- MFMA causal flash attention, 128 queries/block, 32 q/wave ----
// R0: causal load-balance remap (qb reflected on odd bz): 137 -> 96us.
// R1: dbuf K/V + counted vmcnt: NULL; kept (harmless).
// R2: raw v_exp_f32: -3us; VALU savings tracked 1:1 into wall -> attn is
//     issue-serialized through the softmax/P block.
// R3 (this round): NO P LDS ROUND-TRIP. Compute S^T = mfma(K,Q) (operand
//     swap; fragments unchanged since A-frag(X)==B-frag(X^T)). C-layout
//     leaves each lane with P for ONE query (q=l16) at keys {16ni+4quad+r}.
//     cvt_pk pairs -> feed directly as PV B-operand; instead of moving P
//     cross-lane, permute the V reads: k-slot (c,quad,j) of the mfma holds
//     actual key 32c+16(j>>2)+4quad+(j&3), so V A-frags read Vs[d][key] as
//     2x ds_read_b64 per frag (keys 4-consecutive, 16 apart). Deletes:
//     Ps (17KB LDS), 32 ds_write_b16 + 8 ds_read_b64 + 32 scalar cvt + the
//     intra-tile write->read lgkm chain. Output is O^T (d per-lane, q=l16):
//     epilogue packs 8B stores; l-reduce is 2 shfl_xor (lanes sharing l16).
__global__ __launch_bounds__(256) void attn_kernel(
    const __hip_bfloat16* __restrict__ Qb, const __hip_bfloat16* __restrict__ Kb,
    const __hip_bfloat16* __restrict__ Vt, __hip_bfloat16* __restrict__ Yb) {
  __shared__ __align__(16) __hip_bfloat16 Ks[2][64][64];   // [buf][key][d] swizzled
  __shared__ __align__(16) __hip_bfloat16 Vs[2][64][64];   // [buf][d][key] swizzled
  int tid = threadIdx.x;
  int b = blockIdx.z, h = blockIdx.y;
  int qb = (b & 1) ? (TSEQ/128 - 1 - blockIdx.x) : blockIdx.x;  // R0 balance remap
  int q0 = qb*128;
  size_t bhT  = (size_t)(b*N_HEADS + h)*TSEQ;
  size_t bhHD = (size_t)(b*N_HEADS + h)*HD;
  int lane = tid&63, w = tid>>6, l16 = lane&15, quad = lane>>4;
  int wq = w*32;                       // wave's query band
  int xg = l16 & 7;
  int off0 = ((quad    ) ^ xg)*8;      // K-frag d-chunk 0 (physical, swizzled)
  int off1 = ((quad + 4) ^ xg)*8;      // K-frag d-chunk 1
  // V-frag element offsets within a Vs row (see R3 header): per (c, lo/hi)
  int q21 = quad>>1, q1 = (quad&1)*4;
  int vo[2][2];
  vo[0][0] = ((0 + q21) ^ xg)*8 + q1;  // c=0, keys 4quad+0..3
  vo[0][1] = ((2 + q21) ^ xg)*8 + q1;  // c=0, keys 16+4quad+0..3
  vo[1][0] = ((4 + q21) ^ xg)*8 + q1;  // c=1, keys 32+4quad+0..3
  vo[1][1] = ((6 + q21) ^ xg)*8 + q1;  // c=1, keys 48+4quad+0..3

  // staging addresses (per-thread, constant across tiles except k0)
  int slot0 = tid,        row0 = slot0>>3, gcA = ((tid&7) ^ (row0&7))*8;
  int slot1 = 256 + tid,  row1 = slot1>>3, gcB = ((tid&7) ^ (row1&7))*8;

  // Q fragments for 2 q-tiles x 2 d-chunks (used as PV.. QK^T B-operand)
  s16x8 qf[2][2];
  #pragma unroll
  for (int mi=0;mi<2;++mi) {
    const __hip_bfloat16* qrow = Qb + (bhT + q0 + wq + mi*16 + l16)*HD;
    qf[mi][0] = *(const s16x8*)(qrow + quad*8);
    qf[mi][1] = *(const s16x8*)(qrow + 32 + quad*8);
  }

  f32x4 z4 = {0.f,0.f,0.f,0.f};
  f32x4 oacc[4][2];                    // [d-tile nd][mi], O^T layout
  #pragma unroll
  for (int nd=0;nd<4;++nd) { oacc[nd][0]=z4; oacc[nd][1]=z4; }
  float lsum[2] = {0.f, 0.f};          // per-lane partial row sum (16 keys/tile)

  int ntiles = 2*qb + 2;

  // prologue: stage tile 0 into buffer 0 (4 glds16 per thread)
  {
    glds16(Kb + (bhT + 0 + row0)*HD + gcA,    &Ks[0][0][0] + slot0*8);
    glds16(Vt + (bhHD + row0)*TSEQ + 0 + gcA, &Vs[0][0][0] + slot0*8);
    glds16(Kb + (bhT + 0 + row1)*HD + gcB,    &Ks[0][0][0] + slot1*8);
    glds16(Vt + (bhHD + row1)*TSEQ + 0 + gcB, &Vs[0][0][0] + slot1*8);
  }

  for (int t=0; t<ntiles; ++t) {
    int cur = t&1;
    int k0 = t*64;
    // A: issue next tile's staging into the other buffer
    if (t+1 < ntiles) {
      int kn = k0 + 64;
      glds16(Kb + (bhT + kn + row0)*HD + gcA,     &Ks[cur^1][0][0] + slot0*8);
      glds16(Vt + (bhHD + row0)*TSEQ + kn + gcA,  &Vs[cur^1][0][0] + slot0*8);
      glds16(Kb + (bhT + kn + row1)*HD + gcB,     &Ks[cur^1][0][0] + slot1*8);
      glds16(Vt + (bhHD + row1)*TSEQ + kn + gcB,  &Vs[cur^1][0][0] + slot1*8);
      asm volatile("s_waitcnt vmcnt(4)" ::: "memory");
    } else {
      asm volatile("s_waitcnt vmcnt(0)" ::: "memory");
    }
    // C: all waves' cur-buffer loads landed
    __builtin_amdgcn_s_barrier();
    __builtin_amdgcn_sched_barrier(0);

    const __hip_bfloat16* Kc = &Ks[cur][0][0];
    const __hip_bfloat16* Vc = &Vs[cur][0][0];

    // S^T = K Q^T : per wave 64key x 32q.  sacc[ni][mi]: lane holds
    // S^T[key=16ni+4quad+r][q=l16 (+16mi)]
    f32x4 sacc[4][2];
    #pragma unroll
    for (int ni=0; ni<4; ++ni) {
      s16x8 kb0 = *(const s16x8*)(Kc + (ni*16+l16)*64 + off0);
      s16x8 kb1 = *(const s16x8*)(Kc + (ni*16+l16)*64 + off1);
      #pragma unroll
      for (int mi=0; mi<2; ++mi) {
        f32x4 s = z4;
        s = __builtin_amdgcn_mfma_f32_16x16x32_bf16(kb0, qf[mi][0], s,0,0,0);
        s = __builtin_amdgcn_mfma_f32_16x16x32_bf16(kb1, qf[mi][1], s,0,0,0);
        sacc[ni][mi] = s;
      }
    }

    // mask + exp; accumulate lsum; pack P pairs in-register (no LDS)
    unsigned pkw[2][4][2];   // [mi][ni][r-pair]: keys 16ni+4quad+{2p,2p+1}
    if (q0 + wq >= k0 + 63) {
      #pragma unroll
      for (int ni=0; ni<4; ++ni) {
        #pragma unroll
        for (int mi=0; mi<2; ++mi) {
          float e0 = exp_scaled(sacc[ni][mi][0]);
          float e1 = exp_scaled(sacc[ni][mi][1]);
          float e2 = exp_scaled(sacc[ni][mi][2]);
          float e3 = exp_scaled(sacc[ni][mi][3]);
          lsum[mi] += (e0+e1)+(e2+e3);
          pkw[mi][ni][0] = cvtpk(e0, e1);
          pkw[mi][ni][1] = cvtpk(e2, e3);
        }
      }
    } else {
      #pragma unroll
      for (int ni=0; ni<4; ++ni) {
        int kbase = k0 + ni*16 + quad*4;
        #pragma unroll
        for (int mi=0; mi<2; ++mi) {
          int qrow = q0 + wq + mi*16 + l16;
          float e0 = (qrow >= kbase    ) ? exp_scaled(sacc[ni][mi][0]) : 0.f;
          float e1 = (qrow >= kbase + 1) ? exp_scaled(sacc[ni][mi][1]) : 0.f;
          float e2 = (qrow >= kbase + 2) ? exp_scaled(sacc[ni][mi][2]) : 0.f;
          float e3 = (qrow >= kbase + 3) ? exp_scaled(sacc[ni][mi][3]) : 0.f;
          lsum[mi] += (e0+e1)+(e2+e3);
          pkw[mi][ni][0] = cvtpk(e0, e1);
          pkw[mi][ni][1] = cvtpk(e2, e3);
        }
      }
    }

    // O^T += V^T P^T : A = V-frag (row=d), B = P-frag (col=q, in regs).
    union U8 { s16x8 v; unsigned u[4]; uint2 u2[2]; };
    #pragma unroll
    for (int c=0; c<2; ++c) {
      U8 pf0, pf1;
      pf0.u[0] = pkw[0][2*c][0];   pf0.u[1] = pkw[0][2*c][1];
      pf0.u[2] = pkw[0][2*c+1][0]; pf0.u[3] = pkw[0][2*c+1][1];
      pf1.u[0] = pkw[1][2*c][0];   pf1.u[1] = pkw[1][2*c][1];
      pf1.u[2] = pkw[1][2*c+1][0]; pf1.u[3] = pkw[1][2*c+1][1];
      #pragma unroll
      for (int nd=0; nd<4; ++nd) {
        const __hip_bfloat16* vrow = Vc + (nd*16 + l16)*64;
        U8 vf;
        vf.u2[0] = *(const uint2*)(vrow + vo[c][0]);
        vf.u2[1] = *(const uint2*)(vrow + vo[c][1]);
        oacc[nd][0] = __builtin_amdgcn_mfma_f32_16x16x32_bf16(vf.v, pf0.v, oacc[nd][0],0,0,0);
        oacc[nd][1] = __builtin_amdgcn_mfma_f32_16x16x32_bf16(vf.v, pf1.v, oacc[nd][1],0,0,0);
      }
    }

    // E: all frag reads of buf[cur] complete -> safe to restage it next iter
    asm volatile("s_waitcnt lgkmcnt(0)" ::: "memory");
    __builtin_amdgcn_s_barrier();
    __builtin_amdgcn_sched_barrier(0);
  }

  // reduce lsum across the 4 lanes sharing l16 (quads)
  #pragma unroll
  for (int mi=0; mi<2; ++mi) {
    lsum[mi] += __shfl_xor(lsum[mi], 16);
    lsum[mi] += __shfl_xor(lsum[mi], 32);
  }

  // epilogue: lane holds O^T[d=16nd+4quad+r][q=l16+16mi]; pack 4 d-values
  // (8B) per (nd,mi) and store.
  #pragma unroll
  for (int mi=0; mi<2; ++mi) {
    float inv = 1.f / lsum[mi];
    int tq = q0 + wq + mi*16 + l16;
    __hip_bfloat16* yr = Yb + ((size_t)(b*TSEQ + tq))*N_EMBD + h*HD + quad*4;
    #pragma unroll
    for (int nd=0; nd<4; ++nd) {
      uint2 o;
      o.x = cvtpk(oacc[nd][mi][0]*inv, oacc[nd][mi][1]*inv);
      o.y = cvtpk(oacc[nd][mi][2]*inv, oacc[nd][mi][3]*inv);
      *(uint2*)(yr + nd*16) = o;
    }
  }
}

extern "C" void kernel_launch(void* const* d_in, const int* in_sizes, int n_in,
                              void* d_out, int out_size, void* d_ws, size_t ws_size,
                              hipStream_t stream) {
  const float* x  = (const float*)d_in[0];
  const float* Wq = (const float*)d_in[1];
  const float* Wk = (const float*)d_in[2];
  const float* Wv = (const float*)d_in[3];
  const float* Wp = (const float*)d_in[4];
  const float* bp = (const float*)d_in[5];

  char* w = (char*)d_ws;
  __hip_bfloat16* xb    = (__hip_bfloat16*)w;  w += (size_t)M_TOT*N_EMBD*2;   // 16 MB
  __hip_bfloat16* wqkvt = (__hip_bfloat16*)w;  w += (size_t)3*N_EMBD*N_EMBD*2;// 6 MB
  __hip_bfloat16* wpt   = (__hip_bfloat16*)w;  w += (size_t)N_EMBD*N_EMBD*2;  // 2 MB
  __hip_bfloat16* Qb    = (__hip_bfloat16*)w;  w += (size_t)M_TOT*N_EMBD*2;   // 16 MB
  __hip_bfloat16* Kb    = (__hip_bfloat16*)w;  w += (size_t)M_TOT*N_EMBD*2;   // 16 MB
  __hip_bfloat16* Vt    = (__hip_bfloat16*)w;  w += (size_t)M_TOT*N_EMBD*2;   // 16 MB [B,H,d,T]
  __hip_bfloat16* Yb    = (__hip_bfloat16*)w;                                  // 16 MB (88 MB total)

  xcast_kernel<<<dim3(M_TOT*N_EMBD/1024), dim3(256), 0, stream>>>(x, xb);
  wcast_kernel<<<dim3(32,32,4), dim3(32,8), 0, stream>>>(Wq,Wk,Wv,Wp,wqkvt,wpt);
  gemm_kernel<<<dim3(24,64), dim3(256), 0, stream>>>(xb, wqkvt, Qb,Kb,Vt, nullptr, nullptr, 0);
  attn_kernel<<<dim3(TSEQ/128,N_HEADS,BATCH), dim3(256), 0, stream>>>(Qb,Kb,Vt,Yb);
  gemm_kernel<<<dim3(8,64), dim3(256), 0, stream>>>(Yb, wpt, nullptr,nullptr,nullptr,
                                                    (float*)d_out, bp, 1);
}

// Round 5
// 268.868 us; speedup vs baseline: 1.1771x; 1.0073x over previous
//
#include <hip/hip_runtime.h>
#include <hip/hip_bf16.h>

#define N_EMBD 1024
#define N_HEADS 16
#define HD 64
#define TSEQ 2048
#define BATCH 4
#define M_TOT (BATCH*TSEQ)   // 8192

typedef short s16x8 __attribute__((ext_vector_type(8)));
typedef float f32x4 __attribute__((ext_vector_type(4)));

__device__ __forceinline__ void glds16(const void* g, void* l) {
  __builtin_amdgcn_global_load_lds((const __attribute__((address_space(1))) void*)g,
                                   (__attribute__((address_space(3))) void*)l, 16, 0, 0);
}

// exp(s*0.125) = 2^(s * 0.125*log2(e)) via a single hardware v_exp_f32 (R2).
__device__ __forceinline__ float exp_scaled(float s) {
  float r;
  asm("v_exp_f32 %0, %1\n\ts_nop 0" : "=v"(r) : "v"(s * 0.18033688011112042f));
  return r;
}

// pack two f32 -> bf16x2 (src0 in low 16). No builtin on gfx950 (T12/m240).
__device__ __forceinline__ unsigned cvtpk(float lo, float hi) {
  unsigned r;
  asm("v_cvt_pk_bf16_f32 %0, %1, %2" : "=v"(r) : "v"(lo), "v"(hi));
  return r;
}

// ---- cast x fp32 -> bf16, 4 elems/thread ----
__global__ __launch_bounds__(256) void xcast_kernel(const float* __restrict__ x,
                                                    __hip_bfloat16* __restrict__ xb) {
  int i = blockIdx.x * 256 + threadIdx.x;
  float4 f = ((const float4*)x)[i];
  __hip_bfloat162 p0, p1;
  p0.x = __float2bfloat16(f.x); p0.y = __float2bfloat16(f.y);
  p1.x = __float2bfloat16(f.z); p1.y = __float2bfloat16(f.w);
  ((__hip_bfloat162*)xb)[2*i]   = p0;
  ((__hip_bfloat162*)xb)[2*i+1] = p1;
}

// ---- transpose + cast weights: out[n][c] = in[c][n], bf16 ----
__global__ void wcast_kernel(const float* __restrict__ Wq, const float* __restrict__ Wk,
                             const float* __restrict__ Wv, const float* __restrict__ Wp,
                             __hip_bfloat16* __restrict__ wqkvt, __hip_bfloat16* __restrict__ wpt) {
  __shared__ float tile[32][33];
  int z = blockIdx.z;
  const float* in = (z==0)?Wq:(z==1)?Wk:(z==2)?Wv:Wp;
  __hip_bfloat16* out = (z<3) ? (wqkvt + (size_t)z*N_EMBD*N_EMBD) : wpt;
  int tx = threadIdx.x, ty = threadIdx.y;
  int x  = blockIdx.x*32 + tx;
  int y0 = blockIdx.y*32;
  #pragma unroll
  for (int j=0;j<4;++j) tile[ty + j*8][tx] = in[(size_t)(y0+ty+j*8)*N_EMBD + x];
  __syncthreads();
  int xo  = y0 + tx;
  int yo0 = blockIdx.x*32;
  #pragma unroll
  for (int j=0;j<4;++j)
    out[(size_t)(yo0+ty+j*8)*N_EMBD + xo] = __float2bfloat16(tile[tx][ty+j*8]);
}

// ---- bf16 MFMA GEMM, m97-style: 128x128 tile, BK=64, glds16 staging ----
// LDS layout is XOR-swizzled on the GLOBAL fetch side: physical 16B-group g
// holds logical group g^(row&7)  (glds LDS side must stay linear lane*16).
// mode 0: N=3072 (QKV). Q,K scatter [B,H,T,d]; V stored TRANSPOSED [B,H,d,T]
//   with a per-64-key-tile BIT-PERMUTED column order (R4): position p holds
//   key [p5,p2,p4,p3,p1,p0], so attn's in-register P fragments consume V
//   with the standard conflict-free b128 frag reads (K-read pattern).
// mode 1: N=1024 (proj), out fp32 = acc + bias.
__global__ __launch_bounds__(256) void gemm_kernel(
    const __hip_bfloat16* __restrict__ A,   // [M][1024] bf16
    const __hip_bfloat16* __restrict__ Bt,  // [N][1024] bf16 (transposed weight)
    __hip_bfloat16* __restrict__ Qb, __hip_bfloat16* __restrict__ Kb,
    __hip_bfloat16* __restrict__ Vt,        // [B,H,d,T] (key-permuted per 64-tile)
    float* __restrict__ out, const float* __restrict__ bias, int mode) {
  __shared__ __align__(16) char smem[32768];
  __hip_bfloat16* Alin = (__hip_bfloat16*)smem;            // 128x64
  __hip_bfloat16* Blin = (__hip_bfloat16*)(smem + 16384);  // 128x64
  int tid = threadIdx.x;
  int m0 = blockIdx.y*128, n0 = blockIdx.x*128;
  int w = tid>>6, lane = tid&63, l16 = lane&15, quad = lane>>4;
  int wr = w>>1, wc = w&1;
  int xg = l16 & 7;
  int off0 = ((quad    ) ^ xg)*8;   // physical col offset for logical k-chunk 0
  int off1 = ((quad + 4) ^ xg)*8;   // logical group c*4+quad, c=1
  f32x4 acc[4][4];
  #pragma unroll
  for (int mi=0;mi<4;++mi)
    #pragma unroll
    for (int ni=0;ni<4;++ni) acc[mi][ni] = (f32x4){0.f,0.f,0.f,0.f};

  for (int k0=0; k0<N_EMBD; k0+=64) {
    __syncthreads();   // prev frag reads done before restaging
    #pragma unroll
    for (int rd=0; rd<4; ++rd) {
      int slot = rd*256 + tid;
      int row  = slot>>3;
      int gc8  = ((tid&7) ^ (row&7))*8;
      glds16(A  + (size_t)(m0+row)*N_EMBD + k0 + gc8, Alin + slot*8);
      glds16(Bt + (size_t)(n0+row)*N_EMBD + k0 + gc8, Blin + slot*8);
    }
    __syncthreads();   // drain vmcnt
    #pragma unroll
    for (int c=0;c<2;++c) {
      int off = c ? off1 : off0;
      s16x8 af[4], bfr[4];
      #pragma unroll
      for (int mi=0;mi<4;++mi)
        af[mi] = *(const s16x8*)(Alin + (wr*64+mi*16+l16)*64 + off);
      #pragma unroll
      for (int ni=0;ni<4;++ni)
        bfr[ni] = *(const s16x8*)(Blin + (wc*64+ni*16+l16)*64 + off);
      #pragma unroll
      for (int mi=0;mi<4;++mi)
        #pragma unroll
        for (int ni=0;ni<4;++ni)
          acc[mi][ni] = __builtin_amdgcn_mfma_f32_16x16x32_bf16(af[mi], bfr[ni], acc[mi][ni],0,0,0);
    }
  }

  if (mode == 0) {
    int which = n0 >> 10;
    int bb = m0 >> 11, t0 = m0 & 2047;
    if (which < 2) {
      __hip_bfloat16* outp = (which==0)?Qb:Kb;
      #pragma unroll
      for (int mi=0;mi<4;++mi) {
        #pragma unroll
        for (int ni=0;ni<4;++ni) {
          int ncol = (n0 & 1023) + wc*64 + ni*16 + l16;
          int hh = ncol>>6, dd = ncol&63;
          #pragma unroll
          for (int r=0;r<4;++r) {
            int t = t0 + wr*64 + mi*16 + quad*4 + r;
            outp[((size_t)(bb*N_HEADS + hh)*TSEQ + t)*HD + dd] = __float2bfloat16(acc[mi][ni][r]);
          }
        }
      }
    } else {
      // V: transpose 128x128 tile (2 heads) in LDS, store [B,H,d,T] with the
      // R4 per-64-tile key permutation baked in: global position p gets key
      // [p5,p2,p4,p3,p1,p0] (aligned 4-key groups map to aligned 4-key groups,
      // so 8B-vectorized gathers from Ts).
      int hh0 = (n0 & 1023) >> 6;
      __hip_bfloat16 (*Ts)[136] = (__hip_bfloat16(*)[136])smem;  // 64x136x2=17408
      #pragma unroll
      for (int p=0;p<2;++p) {
        __syncthreads();   // Ts region free (prev frag reads / prev pass stores done)
        if (wc == p) {
          #pragma unroll
          for (int mi=0;mi<4;++mi)
            #pragma unroll
            for (int ni=0;ni<4;++ni) {
              int dd = ni*16 + l16;
              #pragma unroll
              for (int r=0;r<4;++r)
                Ts[dd][wr*64 + mi*16 + quad*4 + r] = __float2bfloat16(acc[mi][ni][r]);
            }
        }
        __syncthreads();
        int dd = tid>>2, tc = (tid&3)*32;
        __hip_bfloat16* dst = Vt + ((size_t)(bb*N_HEADS + hh0 + p)*HD + dd)*TSEQ + t0;
        #pragma unroll
        for (int pb=0; pb<8; ++pb) {
          int q  = tc + pb*4;          // position within the 128-col block
          int pp = q & 63;             // within-64-tile position (low 2 bits = 0)
          int key = (q & 64) | (pp & 32) | ((pp & 4) << 2) | ((pp & 24) >> 1);
          *(uint2*)(dst + q) = *(const uint2*)&Ts[dd][key];
        }
      }
    }
  } else {
    #pragma unroll
    for (int mi=0;mi<4;++mi) {
      #pragma unroll
      for (int ni=0;ni<4;++ni) {
        int col = n0 + wc*64 + ni*16 + l16;
        float bs = bias[col];
        #pragma unroll
        for (int r=0;r<4;++r) {
          int m = m0 + wr*64 + mi*16 + quad*4 + r;
          out[(size_t)m*N_EMBD + col] = acc[mi][ni][r] + bs;
        }
      }
    }
  }
}

// ---- MFMA causal flash attention, 128 queries/block, 32 q/wave ----
// R0: causal load-balance remap (qb reflected on odd bz): 137 -> 96us.
// R1: dbuf K/V + counted vmcnt: NULL; kept (harmless).
// R2: raw v_exp_f32: -3us; VALU savings tracked 1:1 into wall -> attn is
//     issue-serialized through the softmax/P block.
// R3: no P LDS round-trip (S^T = mfma(K,Q), cvt_pk P-frags fed straight to
//     PV): 95.5 -> 86.9us, but the permuted b64 V reads introduced 4.45M
//     bank-conflict cycles (Vs row stride = 128B = one bank revolution; b64
//     offsets hit only even bank-pairs, 4 lanes each).
// R4 (this round): key-permutation moved into the Vt GLOBAL layout (see
//     gemm header). V reads become the standard b128 frag reads at off0/off1
//     -- the exact pattern that measures 0 conflicts on the K path. 16 b64
//     -> 8 b128 reads/wave-tile, conflicts -> ~0.
__global__ __launch_bounds__(256) void attn_kernel(
    const __hip_bfloat16* __restrict__ Qb, const __hip_bfloat16* __restrict__ Kb,
    const __hip_bfloat16* __restrict__ Vt, __hip_bfloat16* __restrict__ Yb) {
  __shared__ __align__(16) __hip_bfloat16 Ks[2][64][64];   // [buf][key][d] swizzled
  __shared__ __align__(16) __hip_bfloat16 Vs[2][64][64];   // [buf][d][pos] swizzled
  int tid = threadIdx.x;
  int b = blockIdx.z, h = blockIdx.y;
  int qb = (b & 1) ? (TSEQ/128 - 1 - blockIdx.x) : blockIdx.x;  // R0 balance remap
  int q0 = qb*128;
  size_t bhT  = (size_t)(b*N_HEADS + h)*TSEQ;
  size_t bhHD = (size_t)(b*N_HEADS + h)*HD;
  int lane = tid&63, w = tid>>6, l16 = lane&15, quad = lane>>4;
  int wq = w*32;                       // wave's query band
  int xg = l16 & 7;
  int off0 = ((quad    ) ^ xg)*8;      // logical group quad   (K: d-chunk 0 / V: c=0)
  int off1 = ((quad + 4) ^ xg)*8;      // logical group quad+4 (K: d-chunk 1 / V: c=1)

  // staging addresses (per-thread, constant across tiles except k0)
  int slot0 = tid,        row0 = slot0>>3, gcA = ((tid&7) ^ (row0&7))*8;
  int slot1 = 256 + tid,  row1 = slot1>>3, gcB = ((tid&7) ^ (row1&7))*8;

  // Q fragments for 2 q-tiles x 2 d-chunks (QK^T B-operand)
  s16x8 qf[2][2];
  #pragma unroll
  for (int mi=0;mi<2;++mi) {
    const __hip_bfloat16* qrow = Qb + (bhT + q0 + wq + mi*16 + l16)*HD;
    qf[mi][0] = *(const s16x8*)(qrow + quad*8);
    qf[mi][1] = *(const s16x8*)(qrow + 32 + quad*8);
  }

  f32x4 z4 = {0.f,0.f,0.f,0.f};
  f32x4 oacc[4][2];                    // [d-tile nd][mi], O^T layout
  #pragma unroll
  for (int nd=0;nd<4;++nd) { oacc[nd][0]=z4; oacc[nd][1]=z4; }
  float lsum[2] = {0.f, 0.f};          // per-lane partial row sum (16 keys/tile)

  int ntiles = 2*qb + 2;

  // prologue: stage tile 0 into buffer 0 (4 glds16 per thread)
  {
    glds16(Kb + (bhT + 0 + row0)*HD + gcA,    &Ks[0][0][0] + slot0*8);
    glds16(Vt + (bhHD + row0)*TSEQ + 0 + gcA, &Vs[0][0][0] + slot0*8);
    glds16(Kb + (bhT + 0 + row1)*HD + gcB,    &Ks[0][0][0] + slot1*8);
    glds16(Vt + (bhHD + row1)*TSEQ + 0 + gcB, &Vs[0][0][0] + slot1*8);
  }

  for (int t=0; t<ntiles; ++t) {
    int cur = t&1;
    int k0 = t*64;
    // A: issue next tile's staging into the other buffer
    if (t+1 < ntiles) {
      int kn = k0 + 64;
      glds16(Kb + (bhT + kn + row0)*HD + gcA,     &Ks[cur^1][0][0] + slot0*8);
      glds16(Vt + (bhHD + row0)*TSEQ + kn + gcA,  &Vs[cur^1][0][0] + slot0*8);
      glds16(Kb + (bhT + kn + row1)*HD + gcB,     &Ks[cur^1][0][0] + slot1*8);
      glds16(Vt + (bhHD + row1)*TSEQ + kn + gcB,  &Vs[cur^1][0][0] + slot1*8);
      asm volatile("s_waitcnt vmcnt(4)" ::: "memory");
    } else {
      asm volatile("s_waitcnt vmcnt(0)" ::: "memory");
    }
    // C: all waves' cur-buffer loads landed
    __builtin_amdgcn_s_barrier();
    __builtin_amdgcn_sched_barrier(0);

    const __hip_bfloat16* Kc = &Ks[cur][0][0];
    const __hip_bfloat16* Vc = &Vs[cur][0][0];

    // S^T = K Q^T : per wave 64key x 32q.  sacc[ni][mi]: lane holds
    // S^T[key=16ni+4quad+r][q=l16 (+16mi)]
    f32x4 sacc[4][2];
    #pragma unroll
    for (int ni=0; ni<4; ++ni) {
      s16x8 kb0 = *(const s16x8*)(Kc + (ni*16+l16)*64 + off0);
      s16x8 kb1 = *(const s16x8*)(Kc + (ni*16+l16)*64 + off1);
      #pragma unroll
      for (int mi=0; mi<2; ++mi) {
        f32x4 s = z4;
        s = __builtin_amdgcn_mfma_f32_16x16x32_bf16(kb0, qf[mi][0], s,0,0,0);
        s = __builtin_amdgcn_mfma_f32_16x16x32_bf16(kb1, qf[mi][1], s,0,0,0);
        sacc[ni][mi] = s;
      }
    }

    // mask + exp; accumulate lsum; pack P pairs in-register (no LDS)
    unsigned pkw[2][4][2];   // [mi][ni][r-pair]: keys 16ni+4quad+{2p,2p+1}
    if (q0 + wq >= k0 + 63) {
      #pragma unroll
      for (int ni=0; ni<4; ++ni) {
        #pragma unroll
        for (int mi=0; mi<2; ++mi) {
          float e0 = exp_scaled(sacc[ni][mi][0]);
          float e1 = exp_scaled(sacc[ni][mi][1]);
          float e2 = exp_scaled(sacc[ni][mi][2]);
          float e3 = exp_scaled(sacc[ni][mi][3]);
          lsum[mi] += (e0+e1)+(e2+e3);
          pkw[mi][ni][0] = cvtpk(e0, e1);
          pkw[mi][ni][1] = cvtpk(e2, e3);
        }
      }
    } else {
      #pragma unroll
      for (int ni=0; ni<4; ++ni) {
        int kbase = k0 + ni*16 + quad*4;
        #pragma unroll
        for (int mi=0; mi<2; ++mi) {
          int qrow = q0 + wq + mi*16 + l16;
          float e0 = (qrow >= kbase    ) ? exp_scaled(sacc[ni][mi][0]) : 0.f;
          float e1 = (qrow >= kbase + 1) ? exp_scaled(sacc[ni][mi][1]) : 0.f;
          float e2 = (qrow >= kbase + 2) ? exp_scaled(sacc[ni][mi][2]) : 0.f;
          float e3 = (qrow >= kbase + 3) ? exp_scaled(sacc[ni][mi][3]) : 0.f;
          lsum[mi] += (e0+e1)+(e2+e3);
          pkw[mi][ni][0] = cvtpk(e0, e1);
          pkw[mi][ni][1] = cvtpk(e2, e3);
        }
      }
    }

    // O^T += V^T P^T : A = V-frag (b128, K-read pattern on permuted Vt),
    // B = P-frag (in regs).  k-slot (c,quad,j) <-> key 32c+16(j>>2)+4quad+(j&3)
    // on BOTH operands by construction.
    union U8 { s16x8 v; unsigned u[4]; };
    U8 pf[2][2];   // [c][mi]
    #pragma unroll
    for (int c=0; c<2; ++c)
      #pragma unroll
      for (int mi=0; mi<2; ++mi) {
        pf[c][mi].u[0] = pkw[mi][2*c  ][0];
        pf[c][mi].u[1] = pkw[mi][2*c  ][1];
        pf[c][mi].u[2] = pkw[mi][2*c+1][0];
        pf[c][mi].u[3] = pkw[mi][2*c+1][1];
      }
    #pragma unroll
    for (int nd=0; nd<4; ++nd) {
      const __hip_bfloat16* vrow = Vc + (nd*16 + l16)*64;
      s16x8 vb0 = *(const s16x8*)(vrow + off0);
      s16x8 vb1 = *(const s16x8*)(vrow + off1);
      oacc[nd][0] = __builtin_amdgcn_mfma_f32_16x16x32_bf16(vb0, pf[0][0].v, oacc[nd][0],0,0,0);
      oacc[nd][1] = __builtin_amdgcn_mfma_f32_16x16x32_bf16(vb0, pf[0][1].v, oacc[nd][1],0,0,0);
      oacc[nd][0] = __builtin_amdgcn_mfma_f32_16x16x32_bf16(vb1, pf[1][0].v, oacc[nd][0],0,0,0);
      oacc[nd][1] = __builtin_amdgcn_mfma_f32_16x16x32_bf16(vb1, pf[1][1].v, oacc[nd][1],0,0,0);
    }

    // E: all frag reads of buf[cur] complete -> safe to restage it next iter
    asm volatile("s_waitcnt lgkmcnt(0)" ::: "memory");
    __builtin_amdgcn_s_barrier();
    __builtin_amdgcn_sched_barrier(0);
  }

  // reduce lsum across the 4 lanes sharing l16 (quads)
  #pragma unroll
  for (int mi=0; mi<2; ++mi) {
    lsum[mi] += __shfl_xor(lsum[mi], 16);
    lsum[mi] += __shfl_xor(lsum[mi], 32);
  }

  // epilogue: lane holds O^T[d=16nd+4quad+r][q=l16+16mi]; pack 4 d-values
  // (8B) per (nd,mi) and store.
  #pragma unroll
  for (int mi=0; mi<2; ++mi) {
    float inv = 1.f / lsum[mi];
    int tq = q0 + wq + mi*16 + l16;
    __hip_bfloat16* yr = Yb + ((size_t)(b*TSEQ + tq))*N_EMBD + h*HD + quad*4;
    #pragma unroll
    for (int nd=0; nd<4; ++nd) {
      uint2 o;
      o.x = cvtpk(oacc[nd][mi][0]*inv, oacc[nd][mi][1]*inv);
      o.y = cvtpk(oacc[nd][mi][2]*inv, oacc[nd][mi][3]*inv);
      *(uint2*)(yr + nd*16) = o;
    }
  }
}

extern "C" void kernel_launch(void* const* d_in, const int* in_sizes, int n_in,
                              void* d_out, int out_size, void* d_ws, size_t ws_size,
                              hipStream_t stream) {
  const float* x  = (const float*)d_in[0];
  const float* Wq = (const float*)d_in[1];
  const float* Wk = (const float*)d_in[2];
  const float* Wv = (const float*)d_in[3];
  const float* Wp = (const float*)d_in[4];
  const float* bp = (const float*)d_in[5];

  char* w = (char*)d_ws;
  __hip_bfloat16* xb    = (__hip_bfloat16*)w;  w += (size_t)M_TOT*N_EMBD*2;   // 16 MB
  __hip_bfloat16* wqkvt = (__hip_bfloat16*)w;  w += (size_t)3*N_EMBD*N_EMBD*2;// 6 MB
  __hip_bfloat16* wpt   = (__hip_bfloat16*)w;  w += (size_t)N_EMBD*N_EMBD*2;  // 2 MB
  __hip_bfloat16* Qb    = (__hip_bfloat16*)w;  w += (size_t)M_TOT*N_EMBD*2;   // 16 MB
  __hip_bfloat16* Kb    = (__hip_bfloat16*)w;  w += (size_t)M_TOT*N_EMBD*2;   // 16 MB
  __hip_bfloat16* Vt    = (__hip_bfloat16*)w;  w += (size_t)M_TOT*N_EMBD*2;   // 16 MB [B,H,d,T] permuted
  __hip_bfloat16* Yb    = (__hip_bfloat16*)w;                                  // 16 MB (88 MB total)

  xcast_kernel<<<dim3(M_TOT*N_EMBD/1024), dim3(256), 0, stream>>>(x, xb);
  wcast_kernel<<<dim3(32,32,4), dim3(32,8), 0, stream>>>(Wq,Wk,Wv,Wp,wqkvt,wpt);
  gemm_kernel<<<dim3(24,64), dim3(256), 0, stream>>>(xb, wqkvt, Qb,Kb,Vt, nullptr, nullptr, 0);
  attn_kernel<<<dim3(TSEQ/128,N_HEADS,BATCH), dim3(256), 0, stream>>>(Qb,Kb,Vt,Yb);
  gemm_kernel<<<dim3(8,64), dim3(256), 0, stream>>>(Yb, wpt, nullptr,nullptr,nullptr,
                                                    (float*)d_out, bp, 1);
}

// Round 6
// 239.162 us; speedup vs baseline: 1.3233x; 1.1242x over previous
//
#include <hip/hip_runtime.h>
#include <hip/hip_bf16.h>

#define N_EMBD 1024
#define N_HEADS 16
#define HD 64
#define TSEQ 2048
#define BATCH 4
#define M_TOT (BATCH*TSEQ)   // 8192

typedef short s16x8 __attribute__((ext_vector_type(8)));
typedef float f32x4 __attribute__((ext_vector_type(4)));

__device__ __forceinline__ void glds16(const void* g, void* l) {
  __builtin_amdgcn_global_load_lds((const __attribute__((address_space(1))) void*)g,
                                   (__attribute__((address_space(3))) void*)l, 16, 0, 0);
}

// exp(s*0.125) = 2^(s * 0.125*log2(e)) via a single hardware v_exp_f32 (R2).
__device__ __forceinline__ float exp_scaled(float s) {
  float r;
  asm("v_exp_f32 %0, %1\n\ts_nop 0" : "=v"(r) : "v"(s * 0.18033688011112042f));
  return r;
}

// pack two f32 -> bf16x2 (src0 in low 16). No builtin on gfx950 (T12/m240).
__device__ __forceinline__ unsigned cvtpk(float lo, float hi) {
  unsigned r;
  asm("v_cvt_pk_bf16_f32 %0, %1, %2" : "=v"(r) : "v"(lo), "v"(hi));
  return r;
}

// ---- cast x fp32 -> bf16, 4 elems/thread ----
__global__ __launch_bounds__(256) void xcast_kernel(const float* __restrict__ x,
                                                    __hip_bfloat16* __restrict__ xb) {
  int i = blockIdx.x * 256 + threadIdx.x;
  float4 f = ((const float4*)x)[i];
  __hip_bfloat162 p0, p1;
  p0.x = __float2bfloat16(f.x); p0.y = __float2bfloat16(f.y);
  p1.x = __float2bfloat16(f.z); p1.y = __float2bfloat16(f.w);
  ((__hip_bfloat162*)xb)[2*i]   = p0;
  ((__hip_bfloat162*)xb)[2*i+1] = p1;
}

// ---- transpose + cast weights: out[n][c] = in[c][n], bf16 ----
__global__ void wcast_kernel(const float* __restrict__ Wq, const float* __restrict__ Wk,
                             const float* __restrict__ Wv, const float* __restrict__ Wp,
                             __hip_bfloat16* __restrict__ wqkvt, __hip_bfloat16* __restrict__ wpt) {
  __shared__ float tile[32][33];
  int z = blockIdx.z;
  const float* in = (z==0)?Wq:(z==1)?Wk:(z==2)?Wv:Wp;
  __hip_bfloat16* out = (z<3) ? (wqkvt + (size_t)z*N_EMBD*N_EMBD) : wpt;
  int tx = threadIdx.x, ty = threadIdx.y;
  int x  = blockIdx.x*32 + tx;
  int y0 = blockIdx.y*32;
  #pragma unroll
  for (int j=0;j<4;++j) tile[ty + j*8][tx] = in[(size_t)(y0+ty+j*8)*N_EMBD + x];
  __syncthreads();
  int xo  = y0 + tx;
  int yo0 = blockIdx.x*32;
  #pragma unroll
  for (int j=0;j<4;++j)
    out[(size_t)(yo0+ty+j*8)*N_EMBD + xo] = __float2bfloat16(tile[tx][ty+j*8]);
}

// ---- bf16 MFMA GEMM, m97-style: 128x128 tile, BK=64, glds16 staging ----
// LDS layout is XOR-swizzled on the GLOBAL fetch side: physical 16B-group g
// holds logical group g^(row&7)  (glds LDS side must stay linear lane*16).
// mode 0: N=3072 (QKV). Q,K scatter [B,H,T,d]; V stored TRANSPOSED [B,H,d,T]
//   with a per-64-key-tile BIT-PERMUTED column order (R4): position p holds
//   key [p5,p2,p4,p3,p1,p0], so attn's in-register P fragments consume V
//   with the standard conflict-free b128 frag reads (K-read pattern).
// mode 1: N=1024 (proj), out fp32 = acc + bias.
__global__ __launch_bounds__(256) void gemm_kernel(
    const __hip_bfloat16* __restrict__ A,   // [M][1024] bf16
    const __hip_bfloat16* __restrict__ Bt,  // [N][1024] bf16 (transposed weight)
    __hip_bfloat16* __restrict__ Qb, __hip_bfloat16* __restrict__ Kb,
    __hip_bfloat16* __restrict__ Vt,        // [B,H,d,T] (key-permuted per 64-tile)
    float* __restrict__ out, const float* __restrict__ bias, int mode) {
  __shared__ __align__(16) char smem[32768];
  __hip_bfloat16* Alin = (__hip_bfloat16*)smem;            // 128x64
  __hip_bfloat16* Blin = (__hip_bfloat16*)(smem + 16384);  // 128x64
  int tid = threadIdx.x;
  int m0 = blockIdx.y*128, n0 = blockIdx.x*128;
  int w = tid>>6, lane = tid&63, l16 = lane&15, quad = lane>>4;
  int wr = w>>1, wc = w&1;
  int xg = l16 & 7;
  int off0 = ((quad    ) ^ xg)*8;   // physical col offset for logical k-chunk 0
  int off1 = ((quad + 4) ^ xg)*8;   // logical group c*4+quad, c=1
  f32x4 acc[4][4];
  #pragma unroll
  for (int mi=0;mi<4;++mi)
    #pragma unroll
    for (int ni=0;ni<4;++ni) acc[mi][ni] = (f32x4){0.f,0.f,0.f,0.f};

  for (int k0=0; k0<N_EMBD; k0+=64) {
    __syncthreads();   // prev frag reads done before restaging
    #pragma unroll
    for (int rd=0; rd<4; ++rd) {
      int slot = rd*256 + tid;
      int row  = slot>>3;
      int gc8  = ((tid&7) ^ (row&7))*8;
      glds16(A  + (size_t)(m0+row)*N_EMBD + k0 + gc8, Alin + slot*8);
      glds16(Bt + (size_t)(n0+row)*N_EMBD + k0 + gc8, Blin + slot*8);
    }
    __syncthreads();   // drain vmcnt
    #pragma unroll
    for (int c=0;c<2;++c) {
      int off = c ? off1 : off0;
      s16x8 af[4], bfr[4];
      #pragma unroll
      for (int mi=0;mi<4;++mi)
        af[mi] = *(const s16x8*)(Alin + (wr*64+mi*16+l16)*64 + off);
      #pragma unroll
      for (int ni=0;ni<4;++ni)
        bfr[ni] = *(const s16x8*)(Blin + (wc*64+ni*16+l16)*64 + off);
      #pragma unroll
      for (int mi=0;mi<4;++mi)
        #pragma unroll
        for (int ni=0;ni<4;++ni)
          acc[mi][ni] = __builtin_amdgcn_mfma_f32_16x16x32_bf16(af[mi], bfr[ni], acc[mi][ni],0,0,0);
    }
  }

  if (mode == 0) {
    int which = n0 >> 10;
    int bb = m0 >> 11, t0 = m0 & 2047;
    if (which < 2) {
      __hip_bfloat16* outp = (which==0)?Qb:Kb;
      #pragma unroll
      for (int mi=0;mi<4;++mi) {
        #pragma unroll
        for (int ni=0;ni<4;++ni) {
          int ncol = (n0 & 1023) + wc*64 + ni*16 + l16;
          int hh = ncol>>6, dd = ncol&63;
          #pragma unroll
          for (int r=0;r<4;++r) {
            int t = t0 + wr*64 + mi*16 + quad*4 + r;
            outp[((size_t)(bb*N_HEADS + hh)*TSEQ + t)*HD + dd] = __float2bfloat16(acc[mi][ni][r]);
          }
        }
      }
    } else {
      // V: transpose 128x128 tile (2 heads) in LDS, store [B,H,d,T] with the
      // R4 per-64-tile key permutation baked in: global position p gets key
      // [p5,p2,p4,p3,p1,p0] (aligned 4-key groups map to aligned 4-key groups,
      // so 8B-vectorized gathers from Ts).
      int hh0 = (n0 & 1023) >> 6;
      __hip_bfloat16 (*Ts)[136] = (__hip_bfloat16(*)[136])smem;  // 64x136x2=17408
      #pragma unroll
      for (int p=0;p<2;++p) {
        __syncthreads();   // Ts region free (prev frag reads / prev pass stores done)
        if (wc == p) {
          #pragma unroll
          for (int mi=0;mi<4;++mi)
            #pragma unroll
            for (int ni=0;ni<4;++ni) {
              int dd = ni*16 + l16;
              #pragma unroll
              for (int r=0;r<4;++r)
                Ts[dd][wr*64 + mi*16 + quad*4 + r] = __float2bfloat16(acc[mi][ni][r]);
            }
        }
        __syncthreads();
        int dd = tid>>2, tc = (tid&3)*32;
        __hip_bfloat16* dst = Vt + ((size_t)(bb*N_HEADS + hh0 + p)*HD + dd)*TSEQ + t0;
        #pragma unroll
        for (int pb=0; pb<8; ++pb) {
          int q  = tc + pb*4;          // position within the 128-col block
          int pp = q & 63;             // within-64-tile position (low 2 bits = 0)
          int key = (q & 64) | (pp & 32) | ((pp & 4) << 2) | ((pp & 24) >> 1);
          *(uint2*)(dst + q) = *(const uint2*)&Ts[dd][key];
        }
      }
    }
  } else {
    #pragma unroll
    for (int mi=0;mi<4;++mi) {
      #pragma unroll
      for (int ni=0;ni<4;++ni) {
        int col = n0 + wc*64 + ni*16 + l16;
        float bs = bias[col];
        #pragma unroll
        for (int r=0;r<4;++r) {
          int m = m0 + wr*64 + mi*16 + quad*4 + r;
          out[(size_t)m*N_EMBD + col] = acc[mi][ni][r] + bs;
        }
      }
    }
  }
}

// ---- MFMA causal flash attention, 128 queries/block, 32 q/wave ----
// R0: causal load-balance remap: 137 -> 96us.
// R1: dbuf K/V + counted vmcnt: NULL; kept (harmless).
// R2: raw v_exp_f32: -3us (VALU savings track 1:1 into wall).
// R3: no P LDS round-trip (S^T = mfma(K,Q), in-reg P frags): -9us, but b64
//     V reads cost 4.45M bank-conflict cycles.
// R4: key-permutation baked into Vt global layout; V reads become the
//     conflict-free b128 K-pattern: 86.9 -> 80.7us, conflicts -> 0.
// R5 (this round): OCCUPANCY. Counter showed 18% avg occupancy (5.8/32
//     waves) vs 12 structurally resident: the R0 reflect-remap balanced a
//     4-resident regime, but at 3 blocks/CU + 256 backfill the resident
//     triple sums 36+2bx (unbalanced) and backfill arrives short-last ->
//     long drain tail. Fix: 1D grid, longest-first, sum-equalized perm:
//     qb = perm[wgid>>6], perm = [15,14,13,12,9,8,11,10,4,6,5,7,3,2,1,0].
//     Under the validated stride-256 dispatch model each CU's resident
//     triple {perm[i],perm[i+4],perm[i+8]} sums 28-29 tiles (work 63+-1);
//     backfill = qb {3,2,1,0} descending. Bijective -> correctness-safe.
__global__ __launch_bounds__(256) void attn_kernel(
    const __hip_bfloat16* __restrict__ Qb, const __hip_bfloat16* __restrict__ Kb,
    const __hip_bfloat16* __restrict__ Vt, __hip_bfloat16* __restrict__ Yb) {
  __shared__ __align__(16) __hip_bfloat16 Ks[2][64][64];   // [buf][key][d] swizzled
  __shared__ __align__(16) __hip_bfloat16 Vs[2][64][64];   // [buf][d][pos] swizzled
  int tid = threadIdx.x;
  int wgid = blockIdx.x;
  int qb = (int)((0x01237564AB89CDEFull >> ((wgid>>6)*4)) & 15);  // R5 LJF perm
  int h  = (wgid>>2) & 15;
  int b  = wgid & 3;
  int q0 = qb*128;
  size_t bhT  = (size_t)(b*N_HEADS + h)*TSEQ;
  size_t bhHD = (size_t)(b*N_HEADS + h)*HD;
  int lane = tid&63, w = tid>>6, l16 = lane&15, quad = lane>>4;
  int wq = w*32;                       // wave's query band
  int xg = l16 & 7;
  int off0 = ((quad    ) ^ xg)*8;      // logical group quad   (K: d-chunk 0 / V: c=0)
  int off1 = ((quad + 4) ^ xg)*8;      // logical group quad+4 (K: d-chunk 1 / V: c=1)

  // staging addresses (per-thread, constant across tiles except k0)
  int slot0 = tid,        row0 = slot0>>3, gcA = ((tid&7) ^ (row0&7))*8;
  int slot1 = 256 + tid,  row1 = slot1>>3, gcB = ((tid&7) ^ (row1&7))*8;

  // Q fragments for 2 q-tiles x 2 d-chunks (QK^T B-operand)
  s16x8 qf[2][2];
  #pragma unroll
  for (int mi=0;mi<2;++mi) {
    const __hip_bfloat16* qrow = Qb + (bhT + q0 + wq + mi*16 + l16)*HD;
    qf[mi][0] = *(const s16x8*)(qrow + quad*8);
    qf[mi][1] = *(const s16x8*)(qrow + 32 + quad*8);
  }

  f32x4 z4 = {0.f,0.f,0.f,0.f};
  f32x4 oacc[4][2];                    // [d-tile nd][mi], O^T layout
  #pragma unroll
  for (int nd=0;nd<4;++nd) { oacc[nd][0]=z4; oacc[nd][1]=z4; }
  float lsum[2] = {0.f, 0.f};          // per-lane partial row sum (16 keys/tile)

  int ntiles = 2*qb + 2;

  // prologue: stage tile 0 into buffer 0 (4 glds16 per thread)
  {
    glds16(Kb + (bhT + 0 + row0)*HD + gcA,    &Ks[0][0][0] + slot0*8);
    glds16(Vt + (bhHD + row0)*TSEQ + 0 + gcA, &Vs[0][0][0] + slot0*8);
    glds16(Kb + (bhT + 0 + row1)*HD + gcB,    &Ks[0][0][0] + slot1*8);
    glds16(Vt + (bhHD + row1)*TSEQ + 0 + gcB, &Vs[0][0][0] + slot1*8);
  }

  for (int t=0; t<ntiles; ++t) {
    int cur = t&1;
    int k0 = t*64;
    // A: issue next tile's staging into the other buffer
    if (t+1 < ntiles) {
      int kn = k0 + 64;
      glds16(Kb + (bhT + kn + row0)*HD + gcA,     &Ks[cur^1][0][0] + slot0*8);
      glds16(Vt + (bhHD + row0)*TSEQ + kn + gcA,  &Vs[cur^1][0][0] + slot0*8);
      glds16(Kb + (bhT + kn + row1)*HD + gcB,     &Ks[cur^1][0][0] + slot1*8);
      glds16(Vt + (bhHD + row1)*TSEQ + kn + gcB,  &Vs[cur^1][0][0] + slot1*8);
      asm volatile("s_waitcnt vmcnt(4)" ::: "memory");
    } else {
      asm volatile("s_waitcnt vmcnt(0)" ::: "memory");
    }
    // C: all waves' cur-buffer loads landed
    __builtin_amdgcn_s_barrier();
    __builtin_amdgcn_sched_barrier(0);

    const __hip_bfloat16* Kc = &Ks[cur][0][0];
    const __hip_bfloat16* Vc = &Vs[cur][0][0];

    // S^T = K Q^T : per wave 64key x 32q.  sacc[ni][mi]: lane holds
    // S^T[key=16ni+4quad+r][q=l16 (+16mi)]
    f32x4 sacc[4][2];
    #pragma unroll
    for (int ni=0; ni<4; ++ni) {
      s16x8 kb0 = *(const s16x8*)(Kc + (ni*16+l16)*64 + off0);
      s16x8 kb1 = *(const s16x8*)(Kc + (ni*16+l16)*64 + off1);
      #pragma unroll
      for (int mi=0; mi<2; ++mi) {
        f32x4 s = z4;
        s = __builtin_amdgcn_mfma_f32_16x16x32_bf16(kb0, qf[mi][0], s,0,0,0);
        s = __builtin_amdgcn_mfma_f32_16x16x32_bf16(kb1, qf[mi][1], s,0,0,0);
        sacc[ni][mi] = s;
      }
    }

    // mask + exp; accumulate lsum; pack P pairs in-register (no LDS)
    unsigned pkw[2][4][2];   // [mi][ni][r-pair]: keys 16ni+4quad+{2p,2p+1}
    if (q0 + wq >= k0 + 63) {
      #pragma unroll
      for (int ni=0; ni<4; ++ni) {
        #pragma unroll
        for (int mi=0; mi<2; ++mi) {
          float e0 = exp_scaled(sacc[ni][mi][0]);
          float e1 = exp_scaled(sacc[ni][mi][1]);
          float e2 = exp_scaled(sacc[ni][mi][2]);
          float e3 = exp_scaled(sacc[ni][mi][3]);
          lsum[mi] += (e0+e1)+(e2+e3);
          pkw[mi][ni][0] = cvtpk(e0, e1);
          pkw[mi][ni][1] = cvtpk(e2, e3);
        }
      }
    } else {
      #pragma unroll
      for (int ni=0; ni<4; ++ni) {
        int kbase = k0 + ni*16 + quad*4;
        #pragma unroll
        for (int mi=0; mi<2; ++mi) {
          int qrow = q0 + wq + mi*16 + l16;
          float e0 = (qrow >= kbase    ) ? exp_scaled(sacc[ni][mi][0]) : 0.f;
          float e1 = (qrow >= kbase + 1) ? exp_scaled(sacc[ni][mi][1]) : 0.f;
          float e2 = (qrow >= kbase + 2) ? exp_scaled(sacc[ni][mi][2]) : 0.f;
          float e3 = (qrow >= kbase + 3) ? exp_scaled(sacc[ni][mi][3]) : 0.f;
          lsum[mi] += (e0+e1)+(e2+e3);
          pkw[mi][ni][0] = cvtpk(e0, e1);
          pkw[mi][ni][1] = cvtpk(e2, e3);
        }
      }
    }

    // O^T += V^T P^T : A = V-frag (b128, K-read pattern on permuted Vt),
    // B = P-frag (in regs).  k-slot (c,quad,j) <-> key 32c+16(j>>2)+4quad+(j&3)
    // on BOTH operands by construction.
    union U8 { s16x8 v; unsigned u[4]; };
    U8 pf[2][2];   // [c][mi]
    #pragma unroll
    for (int c=0; c<2; ++c)
      #pragma unroll
      for (int mi=0; mi<2; ++mi) {
        pf[c][mi].u[0] = pkw[mi][2*c  ][0];
        pf[c][mi].u[1] = pkw[mi][2*c  ][1];
        pf[c][mi].u[2] = pkw[mi][2*c+1][0];
        pf[c][mi].u[3] = pkw[mi][2*c+1][1];
      }
    #pragma unroll
    for (int nd=0; nd<4; ++nd) {
      const __hip_bfloat16* vrow = Vc + (nd*16 + l16)*64;
      s16x8 vb0 = *(const s16x8*)(vrow + off0);
      s16x8 vb1 = *(const s16x8*)(vrow + off1);
      oacc[nd][0] = __builtin_amdgcn_mfma_f32_16x16x32_bf16(vb0, pf[0][0].v, oacc[nd][0],0,0,0);
      oacc[nd][1] = __builtin_amdgcn_mfma_f32_16x16x32_bf16(vb0, pf[0][1].v, oacc[nd][1],0,0,0);
      oacc[nd][0] = __builtin_amdgcn_mfma_f32_16x16x32_bf16(vb1, pf[1][0].v, oacc[nd][0],0,0,0);
      oacc[nd][1] = __builtin_amdgcn_mfma_f32_16x16x32_bf16(vb1, pf[1][1].v, oacc[nd][1],0,0,0);
    }

    // E: all frag reads of buf[cur] complete -> safe to restage it next iter
    asm volatile("s_waitcnt lgkmcnt(0)" ::: "memory");
    __builtin_amdgcn_s_barrier();
    __builtin_amdgcn_sched_barrier(0);
  }

  // reduce lsum across the 4 lanes sharing l16 (quads)
  #pragma unroll
  for (int mi=0; mi<2; ++mi) {
    lsum[mi] += __shfl_xor(lsum[mi], 16);
    lsum[mi] += __shfl_xor(lsum[mi], 32);
  }

  // epilogue: lane holds O^T[d=16nd+4quad+r][q=l16+16mi]; pack 4 d-values
  // (8B) per (nd,mi) and store.
  #pragma unroll
  for (int mi=0; mi<2; ++mi) {
    float inv = 1.f / lsum[mi];
    int tq = q0 + wq + mi*16 + l16;
    __hip_bfloat16* yr = Yb + ((size_t)(b*TSEQ + tq))*N_EMBD + h*HD + quad*4;
    #pragma unroll
    for (int nd=0; nd<4; ++nd) {
      uint2 o;
      o.x = cvtpk(oacc[nd][mi][0]*inv, oacc[nd][mi][1]*inv);
      o.y = cvtpk(oacc[nd][mi][2]*inv, oacc[nd][mi][3]*inv);
      *(uint2*)(yr + nd*16) = o;
    }
  }
}

extern "C" void kernel_launch(void* const* d_in, const int* in_sizes, int n_in,
                              void* d_out, int out_size, void* d_ws, size_t ws_size,
                              hipStream_t stream) {
  const float* x  = (const float*)d_in[0];
  const float* Wq = (const float*)d_in[1];
  const float* Wk = (const float*)d_in[2];
  const float* Wv = (const float*)d_in[3];
  const float* Wp = (const float*)d_in[4];
  const float* bp = (const float*)d_in[5];

  char* w = (char*)d_ws;
  __hip_bfloat16* xb    = (__hip_bfloat16*)w;  w += (size_t)M_TOT*N_EMBD*2;   // 16 MB
  __hip_bfloat16* wqkvt = (__hip_bfloat16*)w;  w += (size_t)3*N_EMBD*N_EMBD*2;// 6 MB
  __hip_bfloat16* wpt   = (__hip_bfloat16*)w;  w += (size_t)N_EMBD*N_EMBD*2;  // 2 MB
  __hip_bfloat16* Qb    = (__hip_bfloat16*)w;  w += (size_t)M_TOT*N_EMBD*2;   // 16 MB
  __hip_bfloat16* Kb    = (__hip_bfloat16*)w;  w += (size_t)M_TOT*N_EMBD*2;   // 16 MB
  __hip_bfloat16* Vt    = (__hip_bfloat16*)w;  w += (size_t)M_TOT*N_EMBD*2;   // 16 MB [B,H,d,T] permuted
  __hip_bfloat16* Yb    = (__hip_bfloat16*)w;                                  // 16 MB (88 MB total)

  xcast_kernel<<<dim3(M_TOT*N_EMBD/1024), dim3(256), 0, stream>>>(x, xb);
  wcast_kernel<<<dim3(32,32,4), dim3(32,8), 0, stream>>>(Wq,Wk,Wv,Wp,wqkvt,wpt);
  gemm_kernel<<<dim3(24,64), dim3(256), 0, stream>>>(xb, wqkvt, Qb,Kb,Vt, nullptr, nullptr, 0);
  attn_kernel<<<dim3(1024), dim3(256), 0, stream>>>(Qb,Kb,Vt,Yb);
  gemm_kernel<<<dim3(8,64), dim3(256), 0, stream>>>(Yb, wpt, nullptr,nullptr,nullptr,
                                                    (float*)d_out, bp, 1);
}